// Round 5
// baseline (6152.333 us; speedup 1.0000x reference)
//
#include <hip/hip_runtime.h>
#include <math.h>
#include <cstdint>

// ---------------- constants ----------------
#define CH 191
#define NPIX 65536
#define NPACK 18336            // 191*192/2 packed upper-tri
#define MCOEF 74287            // total wavelet coeffs per channel
#define CSTRIDE 74288
#define SW32 8                 // fp32 Jacobi sweeps
// (fold(a-b), (a+b) mod 191) layout: addr = df*194 + s, df in [0,95], s in [0,191)
// row stride 194: lane strides of phase-2 element runs are +-194+-1 -> +-1/+-3 mod 32
#define NSKEW (96 * 194)       // 18624 fp32 = 74.5 KB

__device__ const float g_dlo[10] = {
  0.003335725285001549f, -0.012580751999015526f, -0.006241490213011705f,
  0.07757149384006515f, -0.03224486958502952f, -0.24229488706619015f,
  0.13842814590110342f, 0.7243085284385744f, 0.6038292697974729f,
  0.160102397974125f };
__device__ const float g_dhi[10] = {
  -0.160102397974125f, 0.6038292697974729f, -0.7243085284385744f,
  0.13842814590110342f, 0.24229488706619015f, -0.03224486958502952f,
  -0.07757149384006515f, -0.006241490213011705f, 0.012580751999015526f,
  0.003335725285001549f };

struct TArgs { double t2[15]; };

__device__ __forceinline__ int pidx(int i, int j) {      // i <= j
  return i * CH - ((i * (i + 1)) >> 1) + j;
}
__device__ __forceinline__ int pidxu(int a, int b) {
  return (a <= b) ? pidx(a, b) : pidx(b, a);
}
// bijective address for unordered pair {a,b}: s=(a+b)%191, df=min(|a-b|,191-|a-b|)
__device__ __forceinline__ int sk(int a, int b) {
  int s = a + b; if (s >= CH) s -= CH;
  int d = a - b; if (d < 0) d = -d;
  int df = (d > 95) ? (CH - d) : d;
  return df * 194 + s;
}

// lgkm-only barrier: per-wave LDS ops drained before signaling; never waits vmcnt,
// so fire-and-forget global stores (rotation logs) don't stall the step loop.
#define BAR_LGKM() asm volatile("s_waitcnt lgkmcnt(0)\n\ts_barrier" ::: "memory")

// ---------------- ddp = X^T X (fp64 accum) ----------------
__global__ __launch_bounds__(256) void k_ddp(const float* __restrict__ x,
                                             double* __restrict__ ddp) {
  __shared__ float as[32][33];
  __shared__ float bs[32][33];
  int i0 = blockIdx.x * 32, j0 = blockIdx.y * 32;
  if (j0 < i0) return;                       // upper tiles only; mirrored later
  int t = threadIdx.x;
  int n0 = blockIdx.z * 4096;
  int tx = t & 15, ty = t >> 4;
  double a00 = 0, a01 = 0, a10 = 0, a11 = 0;
  for (int nb = 0; nb < 4096; nb += 32) {
    for (int e = t; e < 1024; e += 256) {
      int kk = e >> 5, ii = e & 31;
      int n = n0 + nb + kk;
      as[kk][ii] = (i0 + ii < CH) ? x[(size_t)n * CH + i0 + ii] : 0.f;
      bs[kk][ii] = (j0 + ii < CH) ? x[(size_t)n * CH + j0 + ii] : 0.f;
    }
    __syncthreads();
    #pragma unroll 8
    for (int kk = 0; kk < 32; ++kk) {
      double x0 = as[kk][tx], x1 = as[kk][tx + 16];
      double y0 = bs[kk][ty], y1 = bs[kk][ty + 16];
      a00 += x0 * y0; a01 += x0 * y1; a10 += x1 * y0; a11 += x1 * y1;
    }
    __syncthreads();
  }
  int i = i0 + tx, j = j0 + ty;
  if (i < CH) {
    if (j < CH)      atomicAdd(&ddp[i * CH + j], a00);
    if (j + 16 < CH) atomicAdd(&ddp[i * CH + j + 16], a01);
  }
  if (i + 16 < CH) {
    if (j < CH)      atomicAdd(&ddp[(i + 16) * CH + j], a10);
    if (j + 16 < CH) atomicAdd(&ddp[(i + 16) * CH + j + 16], a11);
  }
}

__global__ void k_mirror(double* __restrict__ ddp) {
  int e = blockIdx.x * 256 + threadIdx.x;
  if (e >= CH * CH) return;
  int i = e / CH, j = e % CH;
  if (i > j) ddp[e] = ddp[j * CH + i];
}

__global__ __launch_bounds__(256) void k_rsum(const float* __restrict__ x,
                                              double* __restrict__ rsum) {
  int t = threadIdx.x;
  if (t >= CH) return;
  int row0 = blockIdx.x * 256;
  double a = 0;
  for (int r = 0; r < 256; ++r) a += (double)x[(size_t)(row0 + r) * CH + t];
  atomicAdd(&rsum[t], a);
}

// ---------------- Gauss-Jordan inverse (fp32, in LDS) ----------------
__global__ __launch_bounds__(1024) void k_gj(const double* __restrict__ ddp,
                                             float* __restrict__ out) {
  extern __shared__ char smemraw[];
  float* A = (float*)smemraw;
  float* fc = A + CH * CH;
  int t = threadIdx.x;
  for (int e = t; e < CH * CH; e += 1024) {
    int i = e / CH, j = e % CH;
    A[e] = (float)(ddp[e] + (i == j ? 1e-6 : 0.0));
  }
  __syncthreads();
  for (int k = 0; k < CH; ++k) {
    float pivinv = 1.0f / A[k * CH + k];
    for (int i = t; i < CH; i += 1024) fc[i] = A[i * CH + k];
    __syncthreads();
    for (int j = t; j < CH; j += 1024)
      A[k * CH + j] = (j == k ? 1.0f : A[k * CH + j]) * pivinv;
    __syncthreads();
    for (int e = t; e < CH * CH; e += 1024) {
      int i = e / CH, j = e % CH;
      if (i != k) A[e] = (j == k ? 0.0f : A[e]) - A[k * CH + j] * fc[i];
    }
    __syncthreads();
  }
  for (int e = t; e < CH * CH; e += 1024) out[e] = A[e];
}

// ---------------- one Newton refinement step: P = X(2I - A X), fp64 -------
__global__ void k_newton1(const double* __restrict__ ddp, const float* __restrict__ X,
                          double* __restrict__ T) {
  int j = blockIdx.x * 16 + threadIdx.x, i = blockIdx.y * 16 + threadIdx.y;
  if (i >= CH || j >= CH) return;
  double acc = 0;
  for (int k = 0; k < CH; ++k) {
    double a = ddp[i * CH + k] + (i == k ? 1e-6 : 0.0);
    acc += a * (double)X[k * CH + j];
  }
  T[i * CH + j] = (i == j ? 2.0 : 0.0) - acc;
}
__global__ void k_newton2(const float* __restrict__ X, const double* __restrict__ T,
                          double* __restrict__ P) {
  int j = blockIdx.x * 16 + threadIdx.x, i = blockIdx.y * 16 + threadIdx.y;
  if (i >= CH || j >= CH) return;
  double acc = 0;
  for (int k = 0; k < CH; ++k) acc += (double)X[i * CH + k] * T[k * CH + j];
  P[i * CH + j] = acc;
}

// ---------------- per-band regression -> omega ----------------
__global__ __launch_bounds__(256) void k_beta(const double* __restrict__ ddp,
                                              const double* __restrict__ P,
                                              const double* __restrict__ rsum,
                                              double* __restrict__ sqrtom,
                                              double* __restrict__ invs) {
  __shared__ double bet[CH];
  __shared__ double red[256];
  int i = blockIdx.x, t = threadIdx.x;
  double pii = P[i * CH + i];
  for (int j = t; j < CH; j += 256) {
    double pjip = P[j * CH + i] / pii;
    double acc = 0;
    for (int k = 0; k < CH; ++k) {
      double ddpa = (k == i) ? 0.0 : ddp[k * CH + i];
      acc += (P[j * CH + k] - pjip * P[i * CH + k]) * ddpa;
    }
    bet[j] = (j == i) ? 0.0 : acc;
  }
  __syncthreads();
  double s1 = 0, s2 = 0;
  for (int j = t; j < CH; j += 256) {
    double gj = ((j == i) ? 1.0 : 0.0) - bet[j];
    s1 += gj * rsum[j];
    double tj = 0;
    for (int k = 0; k < CH; ++k) {
      double gk = ((k == i) ? 1.0 : 0.0) - bet[k];
      tj += ddp[j * CH + k] * gk;
    }
    s2 += gj * tj;
  }
  red[t] = s1; __syncthreads();
  for (int o = 128; o; o >>= 1) { if (t < o) red[t] += red[t + o]; __syncthreads(); }
  double sumw = red[0]; __syncthreads();
  red[t] = s2; __syncthreads();
  for (int o = 128; o; o >>= 1) { if (t < o) red[t] += red[t + o]; __syncthreads(); }
  if (t == 0) {
    double sumsq = red[0];
    double var = (sumsq - sumw * sumw / 65536.0) / 65535.0;
    if (var < 0) var = 0;
    double so = sqrt(var) + 1e-30;
    sqrtom[i] = so;
    invs[i] = 1.0 / so;
  }
}

// ---------------- whitened Gram: (df,s)-layout fp32 + diag + full fp64 -----
__global__ void k_packG(const double* __restrict__ ddp, const double* __restrict__ invs,
                        float* __restrict__ Gsk, float* __restrict__ dgf,
                        double* __restrict__ G64) {
  int e = blockIdx.x * 256 + threadIdx.x;
  if (e >= CH * CH) return;
  int i = e / CH, j = e % CH;
  double v = ddp[e] * invs[i] * invs[j];
  G64[e] = v;
  if (j >= i) Gsk[sk(i, j)] = (float)v;
  if (j == i) dgf[i] = (float)v;
}

// ---------------- stage A: single-block fp32 Jacobi, ONE barrier per step --
// Ownership property (verified R1-R4): each off-diag element has exactly one
// owner task per step; step-(r+1) pivots are read by NO step-(r+1) applier;
// diagonals live only in dg[] and are touched only by gen lanes. Hence all
// LDS traffic in a window is owner-exclusive and one barrier/step suffices.
// Threads 1..95 (waves 0-1, compact -- the R3 failure was scattering this)
// each own the one pivot-producing task ((0,2) for t=1, (t-1,t+1) for
// 2<=t<=94, (94,95) for t=95): they apply it, then generate step r+1's
// rotation from the in-register output + dg (csn double-buffered by parity).
// Threads 128..1023 (waves 2-15) apply the remaining 4465 tasks with R4's
// incremental byte addressing. Rotation stream bit-identical to R4 (gen
// consumes the same value the old phase-1 read back from LDS).
__global__ __launch_bounds__(1024) void k_jac32(const float* __restrict__ Gsk,
                                                const float* __restrict__ dg0,
                                                float2* __restrict__ rlogA) {
  extern __shared__ float As[];        // NSKEW floats, (df,s) layout
  __shared__ float2 csn[2][96];
  __shared__ float dg[CH];
  int t = threadIdx.x;
  const int NR = SW32 * CH;

  bool isgen = (t >= 1 && t < 96);
  int jS[5], kS[5]; int ntask = 0;
  if (isgen) {
    jS[0] = (t == 1) ? 0 : (t - 1);
    kS[0] = (t == 1) ? 2 : ((t == 95) ? 95 : (t + 1));
    ntask = 1;
  } else if (t >= 128) {
    // non-gen task enumeration: row j has (j==0 ? 94 : 94-j) tasks
    // (skip k==j+2); prefix(j) = 94j - j(j-1)/2
    int base = t - 128;
    for (int s = 0; s < 5; ++s) {
      int id = base + 896 * s;
      if (id < 4465) {
        int j = 0;
        while (j < 93 && (94 * (j + 1) - ((j + 1) * j) / 2) <= id) ++j;
        int l = id - (94 * j - (j * (j - 1)) / 2);
        int k = (l == 0) ? (j + 1) : (j + 2 + l);
        jS[ntask] = j; kS[ntask] = k; ++ntask;
      }
    }
  }
  // incremental byte addresses, initialized for r=0 (s2r = 0)
  int a00[5], a01[5], a10[5], a11[5], limA[5], limB[5];
  #pragma unroll
  for (int ii = 0; ii < 5; ++ii) {
    if (ii < ntask) {
      int j = jS[ii], k = kS[ii];
      int A = j + k;                          // s-offset for (pj,pk)/(qj,qk)
      int B = k - j;                          // s-offset for (pj,qk)/(qj,pk)
      int dfB = (A > 95) ? (CH - A) : A;      // fold(j+k)
      int bA = B * 194;                       // row of (pj,pk)/(qj,qk)
      int bB = dfB * 194;                     // row of (pj,qk)/(qj,pk)
      a00[ii] = (bA + A) * 4;                 // s00 = A    (A in [1,189])
      a11[ii] = (bA + CH - A) * 4;            // s11 = 191-A
      a01[ii] = (bB + CH - B) * 4;            // s01 = 191-B (B in [1,95])
      a10[ii] = (bB + B) * 4;                 // s10 = B
      limA[ii] = (bA + CH) * 4;
      limB[ii] = (bB + CH) * 4;
    } else {
      a00[ii] = a01[ii] = a10[ii] = a11[ii] = 0;
      limA[ii] = limB[ii] = 1 << 30; jS[ii] = 0; kS[ii] = 1;
    }
  }

  for (int e = t; e < NSKEW; e += 1024) As[e] = Gsk[e];
  if (t < CH) dg[t] = dg0[t];
  __syncthreads();

  // ---- bootstrap: generate step-0 rotations from the initial matrix ----
  if (isgen) {
    int p = t, q = CH - t;                    // r=0 pair
    int ipq = sk(p, q);
    float app = dg[p], aqq = dg[q], apq = As[ipq];
    float c = 1.0f, s = 0.0f, piv = apq, dp = app, dq = aqq;
    if (fabsf(apq) > 3e-7f * (fabsf(app) + fabsf(aqq)) + 1e-30f) {
      float tau = (aqq - app) / (2.0f * apq);
      float tt = copysignf(1.0f, tau) / (fabsf(tau) + sqrtf(1.0f + tau * tau));
      c = 1.0f / sqrtf(1.0f + tt * tt); s = tt * c;
      dp = app - tt * apq; dq = aqq + tt * apq; piv = 0.0f;
    }
    dg[p] = dp; dg[q] = dq;
    csn[0][t] = make_float2(c, s);
    As[ipq] = piv;
    rlogA[t - 1] = make_float2(c, s);
  }
  __syncthreads();

  const char* Asb = (const char*)As;
  int r = 0;
  for (int g = 0; g < NR; ++g) {
    int cur = g & 1, nxt = cur ^ 1;
    // ---- loads: every thread reads only its own task elements ----
    float m0[5], m1[5], m2[5], m3[5];
    #pragma unroll
    for (int ii = 0; ii < 5; ++ii) {
      if (ii < ntask) {
        m0[ii] = *(const float*)(Asb + a00[ii]);
        m1[ii] = *(const float*)(Asb + a01[ii]);
        if (jS[ii] != 0) {
          m2[ii] = *(const float*)(Asb + a10[ii]);
          m3[ii] = *(const float*)(Asb + a11[ii]);
        }
      }
    }
    if (isgen) {
      // ---- apply own task, then generate step r+1's rotation ----
      float2 ck2 = csn[cur][kS[0]];
      float v; int pslot;
      if (t == 1) {                            // task (0,2): 2 elements
        float n0 = ck2.x * m0[0] - ck2.y * m1[0];
        float n1 = ck2.y * m0[0] + ck2.x * m1[0];
        *(float*)((char*)As + a01[0]) = n1;
        v = n0; pslot = a00[0];
      } else {
        float2 cj2 = csn[cur][jS[0]];
        float n00 = ck2.x * m0[0] - ck2.y * m1[0];
        float n01 = ck2.y * m0[0] + ck2.x * m1[0];
        float n10 = ck2.x * m2[0] - ck2.y * m3[0];
        float n11 = ck2.y * m2[0] + ck2.x * m3[0];
        float o00 = cj2.x * n00 - cj2.y * n10, o10 = cj2.y * n00 + cj2.x * n10;
        float o01 = cj2.x * n01 - cj2.y * n11, o11 = cj2.y * n01 + cj2.x * n11;
        *(float*)((char*)As + a00[0]) = o00;
        *(float*)((char*)As + a01[0]) = o01;
        if (t == 95) {                         // task (94,95): pivot is o11
          *(float*)((char*)As + a10[0]) = o10;
          v = o11; pslot = a11[0];
        } else {                               // task (t-1,t+1): pivot is o10
          *(float*)((char*)As + a11[0]) = o11;
          v = o10; pslot = a10[0];
        }
      }
      if (g != NR - 1) {
        int pn = r + 1 + t; if (pn >= CH) pn -= CH;
        int qn = r + 1 - t; if (qn < 0) qn += CH;
        float app = dg[pn], aqq = dg[qn], apq = v;
        float c = 1.0f, s = 0.0f, piv = v, dp = app, dq = aqq;
        if (fabsf(apq) > 3e-7f * (fabsf(app) + fabsf(aqq)) + 1e-30f) {
          float tau = (aqq - app) / (2.0f * apq);
          float tt = copysignf(1.0f, tau) / (fabsf(tau) + sqrtf(1.0f + tau * tau));
          c = 1.0f / sqrtf(1.0f + tt * tt); s = tt * c;
          dp = app - tt * apq; dq = aqq + tt * apq; piv = 0.0f;
        }
        dg[pn] = dp; dg[qn] = dq;
        csn[nxt][t] = make_float2(c, s);
        *(float*)((char*)As + pslot) = piv;
        rlogA[(size_t)(g + 1) * 95 + (t - 1)] = make_float2(c, s);
      } else {
        *(float*)((char*)As + pslot) = v;
      }
      // advance addresses: s += 2 mod 191 => +8B, wrap -764B
      a00[0] += 8; if (a00[0] >= limA[0]) a00[0] -= 764;
      a11[0] += 8; if (a11[0] >= limA[0]) a11[0] -= 764;
      a01[0] += 8; if (a01[0] >= limB[0]) a01[0] -= 764;
      a10[0] += 8; if (a10[0] >= limB[0]) a10[0] -= 764;
    } else {
      // ---- pure apply path (waves 2-15) ----
      #pragma unroll
      for (int ii = 0; ii < 5; ++ii) {
        if (ii < ntask) {
          float2 ck2 = csn[cur][kS[ii]];
          if (jS[ii] == 0) {
            float vp = m0[ii], vq = m1[ii];
            *(float*)((char*)As + a00[ii]) = ck2.x * vp - ck2.y * vq;
            *(float*)((char*)As + a01[ii]) = ck2.y * vp + ck2.x * vq;
          } else {
            float2 cj2 = csn[cur][jS[ii]];
            float n00 = ck2.x * m0[ii] - ck2.y * m1[ii];
            float n01 = ck2.y * m0[ii] + ck2.x * m1[ii];
            float n10 = ck2.x * m2[ii] - ck2.y * m3[ii];
            float n11 = ck2.y * m2[ii] + ck2.x * m3[ii];
            *(float*)((char*)As + a00[ii]) = cj2.x * n00 - cj2.y * n10;
            *(float*)((char*)As + a10[ii]) = cj2.y * n00 + cj2.x * n10;
            *(float*)((char*)As + a01[ii]) = cj2.x * n01 - cj2.y * n11;
            *(float*)((char*)As + a11[ii]) = cj2.y * n01 + cj2.x * n11;
          }
          a00[ii] += 8; if (a00[ii] >= limA[ii]) a00[ii] -= 764;
          a11[ii] += 8; if (a11[ii] >= limA[ii]) a11[ii] -= 764;
          a01[ii] += 8; if (a01[ii] >= limB[ii]) a01[ii] -= 764;
          a10[ii] += 8; if (a10[ii] >= limB[ii]) a10[ii] -= 764;
        }
      }
    }
    ++r; if (r == CH) r = 0;
    BAR_LGKM();
  }
}

// ---------------- replay fp32 rotations -> Q (fp64, raw orientation) ------
// 4-deep global prefetch of the rotation log; lgkm-only barriers so the
// prefetch latency spans 4 rounds instead of stalling each round.
__global__ __launch_bounds__(128) void k_replayA(const float2* __restrict__ rlogA,
                                                 double* __restrict__ Q) {
  __shared__ double vr[CH];
  int row = blockIdx.x, t = threadIdx.x;
  const int NR = SW32 * CH;            // 1528 = 4*382
  for (int j = t; j < CH; j += 128) vr[j] = (j == row) ? 1.0 : 0.0;
  bool act = (t < 95);
  float2 nb[4];
  #pragma unroll
  for (int u = 0; u < 4; ++u)
    nb[u] = act ? rlogA[(size_t)u * 95 + t] : make_float2(1.f, 0.f);
  BAR_LGKM();
  int r = 0;
  for (int g = 0; g < NR; g += 4) {
    #pragma unroll
    for (int u = 0; u < 4; ++u) {
      float2 cur = nb[u];
      int gn = g + u + 4;
      nb[u] = (act && gn < NR) ? rlogA[(size_t)gn * 95 + t] : make_float2(1.f, 0.f);
      if (act && cur.y != 0.f) {
        int k = t + 1;
        int p = r + k; if (p >= CH) p -= CH;
        int q = r - k; if (q < 0) q += CH;
        double s = (double)cur.y;
        double c = sqrt(fmax(0.0, 1.0 - s * s));   // c >= 0.707 always (|t|<=1)
        double vp = vr[p], vq = vr[q];
        vr[p] = c * vp - s * vq;
        vr[q] = s * vp + c * vq;
      }
      if (++r == CH) r = 0;
      BAR_LGKM();
    }
  }
  for (int j = t; j < CH; j += 128) Q[(size_t)row * CH + j] = vr[j];
}

// ---------------- A' = Q^T G Q (fp64, exact repair of fp32 stage) ---------
__global__ void k_gq(const double* __restrict__ G64, const double* __restrict__ Q,
                     double* __restrict__ T) {
  int j = blockIdx.x * 16 + threadIdx.x, i = blockIdx.y * 16 + threadIdx.y;
  if (i >= CH || j >= CH) return;
  double acc = 0;
  for (int k = 0; k < CH; ++k) acc += G64[i * CH + k] * Q[(size_t)k * CH + j];
  T[i * CH + j] = acc;
}
__global__ void k_qtq(const double* __restrict__ Q, const double* __restrict__ T,
                      double* __restrict__ A2p) {
  int j = blockIdx.x * 16 + threadIdx.x, i = blockIdx.y * 16 + threadIdx.y;
  if (i >= CH || j >= CH || j < i) return;
  double acc = 0;
  for (int k = 0; k < CH; ++k) acc += Q[(size_t)k * CH + i] * T[k * CH + j];
  A2p[pidx(i, j)] = acc;
}

// ---------------- stage D: fp64 polish Jacobi (exactly 1 sweep) -----------
__device__ __forceinline__ int Ftri(int j) {
  return 95 * (j - 1) - ((j * (j - 1)) >> 1);
}
__global__ __launch_bounds__(1024) void k_jac64(const double* __restrict__ A2p,
                                                double* __restrict__ eig,
                                                double2* __restrict__ rlogB) {
  extern __shared__ char smemraw[];
  double* Ap = (double*)smemraw;     // 18336
  double* cs = Ap + NPACK;           // 96
  double* sn = cs + 96;              // 96
  int* ps = (int*)(sn + 96);         // 96
  int* qs = ps + 96;                 // 96
  int t = threadIdx.x;

  int code[5]; int ntask = 0;
  for (int task = t; task < 4560; task += 1024) {
    int cde;
    if (task < 4465) {
      int j = (int)((191.0 - sqrt(35721.0 - 8.0 * (double)task)) * 0.5);
      if (j < 1) j = 1;
      while (j < 94 && Ftri(j + 1) <= task) ++j;
      while (j > 1 && Ftri(j) > task) --j;
      int k = j + 1 + (task - Ftri(j));
      cde = (j << 8) | k;
    } else {
      cde = (1 << 20) | (task - 4465 + 1);
    }
    code[ntask++] = cde;
  }

  for (int e = t; e < NPACK; e += 1024) Ap[e] = A2p[e];
  __syncthreads();

  for (int r = 0; r < CH; ++r) {
    if (t >= 1 && t < 96) {
      int k = t;
      int p = r + k; if (p >= CH) p -= CH;
      int q = r + CH - k; if (q >= CH) q -= CH;
      if (p > q) { int tmp = p; p = q; q = tmp; }
      int ipp = pidx(p, p), ipq = pidx(p, q), iqq = pidx(q, q);
      double app = Ap[ipp], apq = Ap[ipq], aqq = Ap[iqq];
      double c = 1.0, s = 0.0;
      if (fabs(apq) > 4e-16 * (fabs(app) + fabs(aqq)) + 1e-300) {
        double tau = (aqq - app) / (2.0 * apq);
        double tt = copysign(1.0, tau) / (fabs(tau) + sqrt(1.0 + tau * tau));
        c = 1.0 / sqrt(1.0 + tt * tt); s = tt * c;
        Ap[ipp] = app - tt * apq;
        Ap[iqq] = aqq + tt * apq;
        Ap[ipq] = 0.0;
      }
      cs[k] = c; sn[k] = s; ps[k] = p; qs[k] = q;
      rlogB[(size_t)r * 95 + (k - 1)] = make_double2(c, s);
    }
    BAR_LGKM();
    int a0 = r;
    #pragma unroll
    for (int ii = 0; ii < 5; ++ii) {
      if (ii < ntask) {
        int cde = code[ii];
        if (cde & (1 << 20)) {
          int k = cde & 0xff;
          double s = sn[k];
          if (s != 0.0) {
            double c = cs[k];
            int iap = pidxu(a0, ps[k]), iaq = pidxu(a0, qs[k]);
            double vp = Ap[iap], vq = Ap[iaq];
            Ap[iap] = c * vp - s * vq;
            Ap[iaq] = s * vp + c * vq;
          }
        } else {
          int j = (cde >> 8) & 0xff, k = cde & 0xff;
          double sj = sn[j], sk_ = sn[k];
          if (sj != 0.0 || sk_ != 0.0) {
            double cj = cs[j], ck = cs[k];
            int pj = ps[j], qj = qs[j], pk = ps[k], qk = qs[k];
            int i00 = pidxu(pj, pk), i01 = pidxu(pj, qk);
            int i10 = pidxu(qj, pk), i11 = pidxu(qj, qk);
            double m00 = Ap[i00], m01 = Ap[i01], m10 = Ap[i10], m11 = Ap[i11];
            double n00 = ck * m00 - sk_ * m01, n01 = sk_ * m00 + ck * m01;
            double n10 = ck * m10 - sk_ * m11, n11 = sk_ * m10 + ck * m11;
            Ap[i00] = cj * n00 - sj * n10;
            Ap[i10] = sj * n00 + cj * n10;
            Ap[i01] = cj * n01 - sj * n11;
            Ap[i11] = sj * n01 + cj * n11;
          }
        }
      }
    }
    BAR_LGKM();
  }
  for (int i = t; i < CH; i += 1024) eig[i] = Ap[pidx(i, i)];
}

// ---------------- apply stage-D rotations to Q rows -> V ------------------
__global__ __launch_bounds__(128) void k_replayB(const double2* __restrict__ rlogB,
                                                 const double* __restrict__ Q,
                                                 double* __restrict__ V) {
  __shared__ double vr[CH];
  int row = blockIdx.x, t = threadIdx.x;
  const int NR = CH;                 // exactly one polish sweep
  for (int j = t; j < CH; j += 128) vr[j] = Q[(size_t)row * CH + j];
  double2 nxt = (t < 95) ? rlogB[t] : make_double2(1.0, 0.0);
  BAR_LGKM();
  for (int g = 0; g < NR; ++g) {
    double2 cur = nxt;
    if (t < 95 && g + 1 < NR) nxt = rlogB[(size_t)(g + 1) * 95 + t];
    if (t < 95 && cur.y != 0.0) {
      int r = g;
      int k = t + 1;
      int p = r + k; if (p >= CH) p -= CH;
      int q = r + CH - k; if (q >= CH) q -= CH;
      if (p > q) { int tmp = p; p = q; q = tmp; }
      double vp = vr[p], vq = vr[q];
      vr[p] = cur.x * vp - cur.y * vq;
      vr[q] = cur.y * vp + cur.x * vq;
    }
    BAR_LGKM();
  }
  for (int j = t; j < CH; j += 128) V[(size_t)row * CH + j] = vr[j];
}

// ---------------- sort eigenpairs (desc) + whitened eigvec matrix ---------
__global__ __launch_bounds__(256) void k_sortprep(const double* __restrict__ eig,
                                                  const double* __restrict__ V,
                                                  const double* __restrict__ invs,
                                                  int* __restrict__ perm,
                                                  float* __restrict__ Vw) {
  __shared__ double ev[CH];
  __shared__ int pm[CH];
  int t = threadIdx.x;
  if (t < CH) ev[t] = eig[t];
  __syncthreads();
  if (t < CH) {
    double my = ev[t];
    int rk = 0;
    for (int j = 0; j < CH; ++j) {
      double o = ev[j];
      rk += (o > my || (o == my && j < t)) ? 1 : 0;
    }
    pm[rk] = t;
  }
  __syncthreads();
  if (t < CH) perm[t] = pm[t];
  for (int e = t; e < 192 * 192; e += 256) {
    int k = e / 192, i = e - k * 192;
    float v = 0.f;
    if (k < CH && i < CH) v = (float)(invs[k] * V[(size_t)k * CH + pm[i]]);
    Vw[e] = v;
  }
}

// ---------------- pcT = (Y V)^T : [CH][NPIX] ----------------
__global__ __launch_bounds__(256) void k_pc(const float* __restrict__ x,
                                            const float* __restrict__ Vw,
                                            float* __restrict__ pcT) {
  __shared__ float xs[16][65];
  __shared__ float vs[16][33];
  int n0 = blockIdx.x * 64, i0 = blockIdx.y * 32;
  int t = threadIdx.x;
  int tn = t & 15, ti = t >> 4;
  float acc[4][2] = {};
  for (int k0 = 0; k0 < 192; k0 += 16) {
    {
      int col = t & 15, row = t >> 4;
      #pragma unroll
      for (int rr = 0; rr < 4; ++rr) {
        int nn = row + rr * 16;
        int k = k0 + col;
        xs[col][nn] = (k < CH) ? x[(size_t)(n0 + nn) * CH + k] : 0.f;
      }
    }
    {
      int ii = t & 31, kk = t >> 5;
      vs[kk][ii] = Vw[(k0 + kk) * 192 + i0 + ii];
      vs[kk + 8][ii] = Vw[(k0 + kk + 8) * 192 + i0 + ii];
    }
    __syncthreads();
    #pragma unroll
    for (int kk = 0; kk < 16; ++kk) {
      float b0 = vs[kk][ti], b1 = vs[kk][ti + 16];
      #pragma unroll
      for (int rr = 0; rr < 4; ++rr) {
        float a = xs[kk][tn + rr * 16];
        acc[rr][0] += a * b0;
        acc[rr][1] += a * b1;
      }
    }
    __syncthreads();
  }
  #pragma unroll
  for (int rr = 0; rr < 4; ++rr)
    #pragma unroll
    for (int bb = 0; bb < 2; ++bb) {
      int i = i0 + ti + bb * 16, n = n0 + tn + rr * 16;
      if (i < CH) pcT[(size_t)i * NPIX + n] = acc[rr][bb];
    }
}

// ---------------- DWT row pass ----------------
__global__ __launch_bounds__(256) void k_row(const float* __restrict__ in,
                                             float* __restrict__ rb,
                                             int h, int w, int wd, int chS) {
  __shared__ float rowv[256];
  int bid = blockIdx.x;
  int c = bid / h, y = bid % h;
  const float* src = in + (size_t)c * chS + (size_t)y * w;
  int t = threadIdx.x;
  if (t < w) rowv[t] = src[t];
  __syncthreads();
  float* dst = rb + (size_t)(c * h + y) * (2 * wd);
  for (int o = t; o < 2 * wd; o += 256) {
    int b = (o >= wd) ? 1 : 0;
    int xp = b ? o - wd : o;
    float acc = 0.f;
    #pragma unroll
    for (int s = 0; s < 10; ++s) {
      int m = 2 * xp + 1 - s;
      if (m < 0) m = -1 - m;
      else if (m >= w) m = 2 * w - 1 - m;
      acc += (b ? g_dhi[s] : g_dlo[s]) * rowv[m];
    }
    dst[o] = acc;
  }
}

// ---------------- DWT column pass: LL out + high bands to coeff -----------
__global__ __launch_bounds__(256) void k_col(const float* __restrict__ rb,
                                             float* __restrict__ llout,
                                             float* __restrict__ coeff,
                                             int h, int wd, int hd, int chSout,
                                             int offHi, int offLL, int lastlvl) {
  int c = blockIdx.z, yp = blockIdx.y;
  int xq = blockIdx.x * 256 + threadIdx.x;
  if (xq >= 2 * wd) return;
  const float* base = rb + (size_t)c * h * 2 * wd + xq;
  float lo = 0.f, hi = 0.f;
  #pragma unroll
  for (int s = 0; s < 10; ++s) {
    int m = 2 * yp + 1 - s;
    if (m < 0) m = -1 - m;
    else if (m >= h) m = 2 * h - 1 - m;
    float v = base[(size_t)m * 2 * wd];
    lo += g_dlo[s] * v;
    hi += g_dhi[s] * v;
  }
  float* cc = coeff + (size_t)c * CSTRIDE;
  if (xq < wd) {
    llout[(size_t)c * chSout + (size_t)yp * wd + xq] = lo;
    if (lastlvl) cc[offLL + yp * wd + xq] = lo;
    cc[offHi + 0 * hd * wd + yp * wd + xq] = hi;
  } else {
    int xp = xq - wd;
    cc[offHi + 1 * hd * wd + yp * wd + xp] = lo;
    cc[offHi + 2 * hd * wd + yp * wd + xp] = hi;
  }
}

// ---------------- SURE statistics (per-thread accumulate, then reduce) ----
__global__ __launch_bounds__(256) void k_stats(const float* __restrict__ coeff,
                                               double* __restrict__ stats, TArgs ta) {
  int c = blockIdx.y;
  const float* cc = coeff + (size_t)c * CSTRIDE;
  double sm[15], cnt[15], nrm = 0;
  #pragma unroll
  for (int q = 0; q < 15; ++q) { sm[q] = 0; cnt[q] = 0; }
  for (int idx = blockIdx.x * 256 + threadIdx.x; idx < MCOEF; idx += 24 * 256) {
    double v = (double)cc[idx];
    double v2 = v * v;
    nrm += v2;
    #pragma unroll
    for (int q = 0; q < 15; ++q) {
      sm[q] += fmin(v2, ta.t2[q]);
      cnt[q] += (v2 >= ta.t2[q]) ? 1.0 : 0.0;
    }
  }
  __shared__ double wred[4][31];
  int lane = threadIdx.x & 63, wv = threadIdx.x >> 6;
  for (int q = 0; q < 31; ++q) {
    double val = (q < 15) ? sm[q] : ((q < 30) ? cnt[q - 15] : nrm);
    #pragma unroll
    for (int o = 32; o > 0; o >>= 1) val += __shfl_down(val, o);
    if (lane == 0) wred[wv][q] = val;
  }
  __syncthreads();
  if (threadIdx.x < 31) {
    double sum = wred[0][threadIdx.x] + wred[1][threadIdx.x] +
                 wred[2][threadIdx.x] + wred[3][threadIdx.x];
    atomicAdd(&stats[c * 31 + threadIdx.x], sum);
  }
}

// ---------------- SURE scan + rank + masked projection matrix -------------
__global__ __launch_bounds__(256) void k_sure(const double* __restrict__ stats,
                                              const double* __restrict__ sqrtom,
                                              const double* __restrict__ V,
                                              const int* __restrict__ perm,
                                              const int* __restrict__ min_iter_p,
                                              float* __restrict__ Wm,
                                              int* __restrict__ meta) {
  __shared__ double st[CH * 31];
  __shared__ double minsure[CH];
  __shared__ int rankS;
  int t = threadIdx.x;
  for (int e = t; e < CH * 31; e += 256) st[e] = stats[e];
  __syncthreads();
  if (t == 0) {
    double norm2 = 0;
    for (int c = 0; c < CH; ++c) norm2 += st[c * 31 + 30];
    double K = norm2 - (double)MCOEF * (double)CH;
    double cum[15];
    for (int q = 0; q < 15; ++q) cum[q] = 0;
    for (int r = 0; r < CH; ++r) {
      double mn = 1e300;
      for (int q = 0; q < 15; ++q) {
        double sure = st[r * 31 + q] + 2.0 * st[r * 31 + 15 + q] - (double)MCOEF;
        double s = cum[q] + sure + K;
        cum[q] += s;
        if (s < mn) mn = s;
      }
      minsure[r] = mn;
    }
    int mi = *min_iter_p;
    int rank = CH - 1;
    for (int r = 0; r < CH; ++r) {
      double prev = (r == 0) ? minsure[0] : minsure[r - 1];
      bool cond = (r > mi) && !(minsure[r] > 2.0 * prev);
      if (cond) { rank = r; break; }
    }
    rankS = rank;
    meta[1] = rank;
  }
  __syncthreads();
  int rank = rankS;
  for (int e = t; e < 192 * 192; e += 256) {
    int k = e / 192, c = e - k * 192;
    float v = 0.f;
    if (k < rank && c < CH) v = (float)(sqrtom[c] * V[(size_t)c * CH + perm[k]]);
    Wm[e] = v;
  }
}

// ---------------- out = pcT^T * Wm ----------------
__global__ __launch_bounds__(256) void k_out(const float* __restrict__ pcT,
                                             const float* __restrict__ Wm,
                                             float* __restrict__ out) {
  __shared__ float psx[16][65];
  __shared__ float wsx[16][33];
  int n0 = blockIdx.x * 64, c0 = blockIdx.y * 32;
  int t = threadIdx.x;
  int tc = t & 15, tn = t >> 4;
  float acc[4][2] = {};
  for (int k0 = 0; k0 < 192; k0 += 16) {
    {
      int nn = t & 63, kk0 = t >> 6;
      #pragma unroll
      for (int rr = 0; rr < 4; ++rr) {
        int kk = kk0 + rr * 4;
        int k = k0 + kk;
        psx[kk][nn] = (k < CH) ? pcT[(size_t)k * NPIX + n0 + nn] : 0.f;
      }
    }
    {
      int cc = t & 31, kk = t >> 5;
      wsx[kk][cc] = Wm[(k0 + kk) * 192 + c0 + cc];
      wsx[kk + 8][cc] = Wm[(k0 + kk + 8) * 192 + c0 + cc];
    }
    __syncthreads();
    #pragma unroll
    for (int kk = 0; kk < 16; ++kk) {
      float b0 = wsx[kk][tc], b1 = wsx[kk][tc + 16];
      #pragma unroll
      for (int rr = 0; rr < 4; ++rr) {
        float a = psx[kk][tn + rr * 16];
        acc[rr][0] += a * b0;
        acc[rr][1] += a * b1;
      }
    }
    __syncthreads();
  }
  #pragma unroll
  for (int rr = 0; rr < 4; ++rr)
    #pragma unroll
    for (int bb = 0; bb < 2; ++bb) {
      int n = n0 + tn + rr * 16, c = c0 + tc + bb * 16;
      if (c < CH) out[(size_t)n * CH + c] = acc[rr][bb];
    }
}

// ---------------- host ----------------
extern "C" void kernel_launch(void* const* d_in, const int* in_sizes, int n_in,
                              void* d_out, int out_size, void* d_ws, size_t ws_size,
                              hipStream_t stream) {
  const float* x = (const float*)d_in[0];
  const int* p_min_iter = (const int*)d_in[1];
  float* out = (float*)d_out;
  char* ws = (char*)d_ws;

  size_t cur = 0;
  auto A = [&](size_t b) { size_t o = cur; cur += (b + 511) & ~(size_t)511; return o; };
  double* ddp     = (double*)(ws + A((size_t)CH * CH * 8));
  double* ddpi64  = (double*)(ws + A((size_t)CH * CH * 8));
  double* Tm      = (double*)(ws + A((size_t)CH * CH * 8));
  double* V       = (double*)(ws + A((size_t)CH * CH * 8));
  double* G64     = (double*)(ws + A((size_t)CH * CH * 8));
  double* T64     = (double*)(ws + A((size_t)CH * CH * 8));
  double* Q       = (double*)(ws + A((size_t)CH * CH * 8));
  double* A2p     = (double*)(ws + A((size_t)NPACK * 8));
  double* eig     = (double*)(ws + A((size_t)CH * 8));
  double* rsum    = (double*)(ws + A((size_t)CH * 8));
  double* sqrtom  = (double*)(ws + A((size_t)CH * 8));
  double* invs    = (double*)(ws + A((size_t)CH * 8));
  double* stats   = (double*)(ws + A((size_t)CH * 31 * 8));
  int* perm       = (int*)(ws + A((size_t)CH * 4));
  int* meta       = (int*)(ws + A(64));
  float* ddpi32   = (float*)(ws + A((size_t)CH * CH * 4));
  float* Gsk      = (float*)(ws + A((size_t)NSKEW * 4));
  float* dgf      = (float*)(ws + A((size_t)CH * 4));
  float* Vw       = (float*)(ws + A((size_t)192 * 192 * 4));
  float* Wm       = (float*)(ws + A((size_t)192 * 192 * 4));
  float2* rlogA   = (float2*)(ws + A((size_t)SW32 * CH * 95 * 8));
  double2* rlogB  = (double2*)(ws + A((size_t)CH * 95 * 16));
  float* pcT      = (float*)(ws + A((size_t)CH * NPIX * 4));
  float* rowbuf   = (float*)(ws + A((size_t)CH * 256 * 264 * 4));
  float* llA      = (float*)(ws + A((size_t)CH * 17424 * 4));
  float* llB      = (float*)(ws + A((size_t)CH * 4900 * 4));
  float* coeff    = (float*)(ws + A((size_t)CH * CSTRIDE * 4));
  (void)ws_size; (void)in_sizes; (void)n_in; (void)out_size;

  hipMemsetAsync(ddp, 0, (size_t)CH * CH * 8, stream);
  hipMemsetAsync(rsum, 0, (size_t)CH * 8, stream);
  hipMemsetAsync(stats, 0, (size_t)CH * 31 * 8, stream);

  const int GJ_SMEM = (CH * CH + CH) * 4;                       // 146688
  const int J32_SMEM = NSKEW * 4;                               // 74496
  const int J64_SMEM = (NPACK + 96 + 96) * 8 + (96 + 96) * 4 + 256;

  k_ddp<<<dim3(6, 6, 16), 256, 0, stream>>>(x, ddp);
  k_mirror<<<143, 256, 0, stream>>>(ddp);
  k_rsum<<<256, 256, 0, stream>>>(x, rsum);
  (void)hipFuncSetAttribute((const void*)k_gj,
        hipFuncAttributeMaxDynamicSharedMemorySize, GJ_SMEM);
  k_gj<<<1, 1024, GJ_SMEM, stream>>>(ddp, ddpi32);
  k_newton1<<<dim3(12, 12), dim3(16, 16), 0, stream>>>(ddp, ddpi32, Tm);
  k_newton2<<<dim3(12, 12), dim3(16, 16), 0, stream>>>(ddpi32, Tm, ddpi64);
  k_beta<<<CH, 256, 0, stream>>>(ddp, ddpi64, rsum, sqrtom, invs);
  k_packG<<<143, 256, 0, stream>>>(ddp, invs, Gsk, dgf, G64);
  (void)hipFuncSetAttribute((const void*)k_jac32,
        hipFuncAttributeMaxDynamicSharedMemorySize, J32_SMEM);
  k_jac32<<<1, 1024, J32_SMEM, stream>>>(Gsk, dgf, rlogA);
  k_replayA<<<CH, 128, 0, stream>>>(rlogA, Q);
  k_gq<<<dim3(12, 12), dim3(16, 16), 0, stream>>>(G64, Q, T64);
  k_qtq<<<dim3(12, 12), dim3(16, 16), 0, stream>>>(Q, T64, A2p);
  (void)hipFuncSetAttribute((const void*)k_jac64,
        hipFuncAttributeMaxDynamicSharedMemorySize, J64_SMEM);
  k_jac64<<<1, 1024, J64_SMEM, stream>>>(A2p, eig, rlogB);
  k_replayB<<<CH, 128, 0, stream>>>(rlogB, Q, V);
  k_sortprep<<<1, 256, 0, stream>>>(eig, V, invs, perm, Vw);
  k_pc<<<dim3(1024, 6), 256, 0, stream>>>(x, Vw, pcT);

  int hs[6] = {256, 132, 70, 39, 24, 16};
  int offHi[5];
  { int a0 = 0; for (int l = 0; l < 5; ++l) { offHi[l] = a0; a0 += 3 * hs[l + 1] * hs[l + 1]; } }
  const int offLL = 74031;
  float* lls[6] = {pcT, llA, llB, llA, llB, llA};
  for (int l = 0; l < 5; ++l) {
    int h = hs[l], w = hs[l], wd = hs[l + 1], hd = hs[l + 1];
    k_row<<<CH * h, 256, 0, stream>>>(lls[l], rowbuf, h, w, wd, h * w);
    k_col<<<dim3((2 * wd + 255) / 256, hd, CH), 256, 0, stream>>>(
        rowbuf, lls[l + 1], coeff, h, wd, hd, hd * wd, offHi[l], offLL,
        (l == 4) ? 1 : 0);
  }

  TArgs ta;
  {
    double tmax = sqrt(log((double)MCOEF));
    for (int j = 0; j < 15; ++j) { double tv = tmax * j / 14.0; ta.t2[j] = tv * tv; }
  }
  k_stats<<<dim3(24, CH), 256, 0, stream>>>(coeff, stats, ta);
  k_sure<<<1, 256, 0, stream>>>(stats, sqrtom, V, perm, p_min_iter, Wm, meta);
  k_out<<<dim3(1024, 6), 256, 0, stream>>>(pcT, Wm, out);
}

// Round 6
// 5539.240 us; speedup vs baseline: 1.1107x; 1.1107x over previous
//
#include <hip/hip_runtime.h>
#include <math.h>
#include <cstdint>

// ---------------- constants ----------------
#define CH 191
#define NPIX 65536
#define NPACK 18336            // 191*192/2 packed upper-tri
#define MCOEF 74287            // total wavelet coeffs per channel
#define CSTRIDE 74288
#define SW32 7                 // fp32 Jacobi sweeps (8->7: fp64 repair absorbs it;
                               // absmax floor is set by fp32 GEMM paths, not Jacobi)
// (fold(a-b), (a+b) mod 191) layout: addr = df*194 + s, df in [0,95], s in [0,191)
// row stride 194: lane strides of phase-2 element runs are +-194+-1 -> +-1/+-3 mod 32
#define NSKEW (96 * 194)       // 18624 fp32 = 74.5 KB

__device__ const float g_dlo[10] = {
  0.003335725285001549f, -0.012580751999015526f, -0.006241490213011705f,
  0.07757149384006515f, -0.03224486958502952f, -0.24229488706619015f,
  0.13842814590110342f, 0.7243085284385744f, 0.6038292697974729f,
  0.160102397974125f };
__device__ const float g_dhi[10] = {
  -0.160102397974125f, 0.6038292697974729f, -0.7243085284385744f,
  0.13842814590110342f, 0.24229488706619015f, -0.03224486958502952f,
  -0.07757149384006515f, -0.006241490213011705f, 0.012580751999015526f,
  0.003335725285001549f };

struct TArgs { double t2[15]; };

__device__ __forceinline__ int pidx(int i, int j) {      // i <= j
  return i * CH - ((i * (i + 1)) >> 1) + j;
}
__device__ __forceinline__ int pidxu(int a, int b) {
  return (a <= b) ? pidx(a, b) : pidx(b, a);
}
// bijective address for unordered pair {a,b}: s=(a+b)%191, df=min(|a-b|,191-|a-b|)
__device__ __forceinline__ int sk(int a, int b) {
  int s = a + b; if (s >= CH) s -= CH;
  int d = a - b; if (d < 0) d = -d;
  int df = (d > 95) ? (CH - d) : d;
  return df * 194 + s;
}

// lgkm-only barrier: per-wave LDS ops drained before signaling; never waits vmcnt,
// so fire-and-forget global stores (rotation logs) don't stall the step loop.
#define BAR_LGKM() asm volatile("s_waitcnt lgkmcnt(0)\n\ts_barrier" ::: "memory")

// ---------------- ddp = X^T X (fp64 accum) ----------------
__global__ __launch_bounds__(256) void k_ddp(const float* __restrict__ x,
                                             double* __restrict__ ddp) {
  __shared__ float as[32][33];
  __shared__ float bs[32][33];
  int i0 = blockIdx.x * 32, j0 = blockIdx.y * 32;
  if (j0 < i0) return;                       // upper tiles only; mirrored later
  int t = threadIdx.x;
  int n0 = blockIdx.z * 4096;
  int tx = t & 15, ty = t >> 4;
  double a00 = 0, a01 = 0, a10 = 0, a11 = 0;
  for (int nb = 0; nb < 4096; nb += 32) {
    for (int e = t; e < 1024; e += 256) {
      int kk = e >> 5, ii = e & 31;
      int n = n0 + nb + kk;
      as[kk][ii] = (i0 + ii < CH) ? x[(size_t)n * CH + i0 + ii] : 0.f;
      bs[kk][ii] = (j0 + ii < CH) ? x[(size_t)n * CH + j0 + ii] : 0.f;
    }
    __syncthreads();
    #pragma unroll 8
    for (int kk = 0; kk < 32; ++kk) {
      double x0 = as[kk][tx], x1 = as[kk][tx + 16];
      double y0 = bs[kk][ty], y1 = bs[kk][ty + 16];
      a00 += x0 * y0; a01 += x0 * y1; a10 += x1 * y0; a11 += x1 * y1;
    }
    __syncthreads();
  }
  int i = i0 + tx, j = j0 + ty;
  if (i < CH) {
    if (j < CH)      atomicAdd(&ddp[i * CH + j], a00);
    if (j + 16 < CH) atomicAdd(&ddp[i * CH + j + 16], a01);
  }
  if (i + 16 < CH) {
    if (j < CH)      atomicAdd(&ddp[(i + 16) * CH + j], a10);
    if (j + 16 < CH) atomicAdd(&ddp[(i + 16) * CH + j + 16], a11);
  }
}

__global__ void k_mirror(double* __restrict__ ddp) {
  int e = blockIdx.x * 256 + threadIdx.x;
  if (e >= CH * CH) return;
  int i = e / CH, j = e % CH;
  if (i > j) ddp[e] = ddp[j * CH + i];
}

__global__ __launch_bounds__(256) void k_rsum(const float* __restrict__ x,
                                              double* __restrict__ rsum) {
  int t = threadIdx.x;
  if (t >= CH) return;
  int row0 = blockIdx.x * 256;
  double a = 0;
  for (int r = 0; r < 256; ++r) a += (double)x[(size_t)(row0 + r) * CH + t];
  atomicAdd(&rsum[t], a);
}

// ---------------- Gauss-Jordan inverse (fp32, in LDS) ----------------
__global__ __launch_bounds__(1024) void k_gj(const double* __restrict__ ddp,
                                             float* __restrict__ out) {
  extern __shared__ char smemraw[];
  float* A = (float*)smemraw;
  float* fc = A + CH * CH;
  int t = threadIdx.x;
  for (int e = t; e < CH * CH; e += 1024) {
    int i = e / CH, j = e % CH;
    A[e] = (float)(ddp[e] + (i == j ? 1e-6 : 0.0));
  }
  __syncthreads();
  for (int k = 0; k < CH; ++k) {
    float pivinv = 1.0f / A[k * CH + k];
    for (int i = t; i < CH; i += 1024) fc[i] = A[i * CH + k];
    __syncthreads();
    for (int j = t; j < CH; j += 1024)
      A[k * CH + j] = (j == k ? 1.0f : A[k * CH + j]) * pivinv;
    __syncthreads();
    for (int e = t; e < CH * CH; e += 1024) {
      int i = e / CH, j = e % CH;
      if (i != k) A[e] = (j == k ? 0.0f : A[e]) - A[k * CH + j] * fc[i];
    }
    __syncthreads();
  }
  for (int e = t; e < CH * CH; e += 1024) out[e] = A[e];
}

// ---------------- one Newton refinement step: P = X(2I - A X), fp64 -------
__global__ void k_newton1(const double* __restrict__ ddp, const float* __restrict__ X,
                          double* __restrict__ T) {
  int j = blockIdx.x * 16 + threadIdx.x, i = blockIdx.y * 16 + threadIdx.y;
  if (i >= CH || j >= CH) return;
  double acc = 0;
  for (int k = 0; k < CH; ++k) {
    double a = ddp[i * CH + k] + (i == k ? 1e-6 : 0.0);
    acc += a * (double)X[k * CH + j];
  }
  T[i * CH + j] = (i == j ? 2.0 : 0.0) - acc;
}
__global__ void k_newton2(const float* __restrict__ X, const double* __restrict__ T,
                          double* __restrict__ P) {
  int j = blockIdx.x * 16 + threadIdx.x, i = blockIdx.y * 16 + threadIdx.y;
  if (i >= CH || j >= CH) return;
  double acc = 0;
  for (int k = 0; k < CH; ++k) acc += (double)X[i * CH + k] * T[k * CH + j];
  P[i * CH + j] = acc;
}

// ---------------- per-band regression -> omega ----------------
__global__ __launch_bounds__(256) void k_beta(const double* __restrict__ ddp,
                                              const double* __restrict__ P,
                                              const double* __restrict__ rsum,
                                              double* __restrict__ sqrtom,
                                              double* __restrict__ invs) {
  __shared__ double bet[CH];
  __shared__ double red[256];
  int i = blockIdx.x, t = threadIdx.x;
  double pii = P[i * CH + i];
  for (int j = t; j < CH; j += 256) {
    double pjip = P[j * CH + i] / pii;
    double acc = 0;
    for (int k = 0; k < CH; ++k) {
      double ddpa = (k == i) ? 0.0 : ddp[k * CH + i];
      acc += (P[j * CH + k] - pjip * P[i * CH + k]) * ddpa;
    }
    bet[j] = (j == i) ? 0.0 : acc;
  }
  __syncthreads();
  double s1 = 0, s2 = 0;
  for (int j = t; j < CH; j += 256) {
    double gj = ((j == i) ? 1.0 : 0.0) - bet[j];
    s1 += gj * rsum[j];
    double tj = 0;
    for (int k = 0; k < CH; ++k) {
      double gk = ((k == i) ? 1.0 : 0.0) - bet[k];
      tj += ddp[j * CH + k] * gk;
    }
    s2 += gj * tj;
  }
  red[t] = s1; __syncthreads();
  for (int o = 128; o; o >>= 1) { if (t < o) red[t] += red[t + o]; __syncthreads(); }
  double sumw = red[0]; __syncthreads();
  red[t] = s2; __syncthreads();
  for (int o = 128; o; o >>= 1) { if (t < o) red[t] += red[t + o]; __syncthreads(); }
  if (t == 0) {
    double sumsq = red[0];
    double var = (sumsq - sumw * sumw / 65536.0) / 65535.0;
    if (var < 0) var = 0;
    double so = sqrt(var) + 1e-30;
    sqrtom[i] = so;
    invs[i] = 1.0 / so;
  }
}

// ---------------- whitened Gram: (df,s)-layout fp32 + diag + full fp64 -----
__global__ void k_packG(const double* __restrict__ ddp, const double* __restrict__ invs,
                        float* __restrict__ Gsk, float* __restrict__ dgf,
                        double* __restrict__ G64) {
  int e = blockIdx.x * 256 + threadIdx.x;
  if (e >= CH * CH) return;
  int i = e / CH, j = e % CH;
  double v = ddp[e] * invs[i] * invs[j];
  G64[e] = v;
  if (j >= i) Gsk[sk(i, j)] = (float)v;
  if (j == i) dgf[i] = (float)v;
}

// ---------------- stage A: single-block fp32 Jacobi (two-phase, R4 struct) --
// Proven structure: loads hoisted before phase-1, two lgkm barriers/step.
// Diagonals live in dg[CH] (phase-1 reads lane-consecutive, conflict-free;
// As holds off-diag only). The 4 element addresses per task are INCREMENTAL
// byte addresses: s advances by +2 mod 191 per step => addr += 8 bytes, wrap
// (-=764) when crossing row base + 191*4.
__global__ __launch_bounds__(1024) void k_jac32(const float* __restrict__ Gsk,
                                                const float* __restrict__ dg0,
                                                float2* __restrict__ rlogA) {
  extern __shared__ float As[];        // NSKEW floats, (df,s) layout
  __shared__ float2 csn[96];
  __shared__ float dg[CH];
  int t = threadIdx.x;

  int jS[5], kS[5]; int ntask = 0;
  for (int id = t; id < 4560; id += 1024) {
    int j = 0, off = 0;
    while (off + (95 - j) <= id) { off += 95 - j; ++j; }
    jS[ntask] = j; kS[ntask] = j + 1 + (id - off);
    ++ntask;
  }
  // incremental byte addresses, initialized for r=0 (s2r = 0)
  int a00[5], a01[5], a10[5], a11[5], limA[5], limB[5];
  #pragma unroll
  for (int ii = 0; ii < 5; ++ii) {
    if (ii < ntask) {
      int j = jS[ii], k = kS[ii];
      int A = j + k;                          // s-offset for (pj,pk)/(qj,qk)
      int B = k - j;                          // s-offset for (pj,qk)/(qj,pk)
      int dfB = (A > 95) ? (CH - A) : A;      // fold(j+k)
      int bA = B * 194;                       // row of (pj,pk)/(qj,qk)
      int bB = dfB * 194;                     // row of (pj,qk)/(qj,pk)
      a00[ii] = (bA + A) * 4;                 // s00 = A    (A in [1,189])
      a11[ii] = (bA + CH - A) * 4;            // s11 = 191-A
      a01[ii] = (bB + CH - B) * 4;            // s01 = 191-B (B in [1,95])
      a10[ii] = (bB + B) * 4;                 // s10 = B
      limA[ii] = (bA + CH) * 4;
      limB[ii] = (bB + CH) * 4;
    } else {
      a00[ii] = a01[ii] = a10[ii] = a11[ii] = 0;
      limA[ii] = limB[ii] = 1 << 30; jS[ii] = 0; kS[ii] = 1;
    }
  }

  for (int e = t; e < NSKEW; e += 1024) As[e] = Gsk[e];
  if (t < CH) dg[t] = dg0[t];
  __syncthreads();

  const char* Asb = (const char*)As;
  for (int sweep = 0; sweep < SW32; ++sweep) {
    for (int r = 0; r < CH; ++r) {
      // ---- pre-barrier: issue this step's element loads (disjoint from
      //      phase-1's pivot/diag set -> race-free; R1-proven) ----
      float m0[5], m1[5], m2[5], m3[5];
      #pragma unroll
      for (int ii = 0; ii < 5; ++ii) {
        if (ii < ntask) {
          m0[ii] = *(const float*)(Asb + a00[ii]);
          m1[ii] = *(const float*)(Asb + a01[ii]);
          if (jS[ii] != 0) {
            m2[ii] = *(const float*)(Asb + a10[ii]);
            m3[ii] = *(const float*)(Asb + a11[ii]);
          }
        }
      }
      // ---- phase 1: rotation generation on lanes 1..95 (waves 0-1 only) ----
      if (t >= 1 && t < 96) {
        int p = r + t; if (p >= CH) p -= CH;
        int q = r - t; if (q < 0) q += CH;
        int ipq = sk(p, q);
        float app = dg[p], aqq = dg[q], apq = As[ipq];
        float c = 1.0f, s = 0.0f, piv = apq, dp = app, dq = aqq;
        if (fabsf(apq) > 3e-7f * (fabsf(app) + fabsf(aqq)) + 1e-30f) {
          float tau = (aqq - app) / (2.0f * apq);
          float tt = copysignf(1.0f, tau) / (fabsf(tau) + sqrtf(1.0f + tau * tau));
          c = 1.0f / sqrtf(1.0f + tt * tt); s = tt * c;
          dp = app - tt * apq; dq = aqq + tt * apq; piv = 0.0f;
        }
        dg[p] = dp; dg[q] = dq;
        As[ipq] = piv;
        csn[t] = make_float2(c, s);
        rlogA[((size_t)(sweep * CH + r)) * 95 + (t - 1)] = make_float2(c, s);
      }
      BAR_LGKM();
      // ---- phase 2: apply rotations (branch-free identity exact) ----
      #pragma unroll
      for (int ii = 0; ii < 5; ++ii) {
        if (ii < ntask) {
          float2 ck2 = csn[kS[ii]];
          if (jS[ii] == 0) {
            float vp = m0[ii], vq = m1[ii];
            *(float*)((char*)As + a00[ii]) = ck2.x * vp - ck2.y * vq;
            *(float*)((char*)As + a01[ii]) = ck2.y * vp + ck2.x * vq;
          } else {
            float2 cj2 = csn[jS[ii]];
            float n00 = ck2.x * m0[ii] - ck2.y * m1[ii];
            float n01 = ck2.y * m0[ii] + ck2.x * m1[ii];
            float n10 = ck2.x * m2[ii] - ck2.y * m3[ii];
            float n11 = ck2.y * m2[ii] + ck2.x * m3[ii];
            *(float*)((char*)As + a00[ii]) = cj2.x * n00 - cj2.y * n10;
            *(float*)((char*)As + a10[ii]) = cj2.y * n00 + cj2.x * n10;
            *(float*)((char*)As + a01[ii]) = cj2.x * n01 - cj2.y * n11;
            *(float*)((char*)As + a11[ii]) = cj2.y * n01 + cj2.x * n11;
          }
          // advance addresses to next step: s += 2 mod 191 => +8B, wrap -764B
          a00[ii] += 8; if (a00[ii] >= limA[ii]) a00[ii] -= 764;
          a11[ii] += 8; if (a11[ii] >= limA[ii]) a11[ii] -= 764;
          a01[ii] += 8; if (a01[ii] >= limB[ii]) a01[ii] -= 764;
          a10[ii] += 8; if (a10[ii] >= limB[ii]) a10[ii] -= 764;
        }
      }
      BAR_LGKM();
    }
  }
}

// ---------------- replay fp32 rotations -> Q (fp64, raw orientation) ------
// 4-deep global prefetch of the rotation log; lgkm-only barriers so the
// prefetch latency spans 4 rounds instead of stalling each round.
// NR need not be a multiple of 4: out-of-range prefetch slots are filled with
// identity (c=1,s=0) and their rotations are no-ops.
__global__ __launch_bounds__(128) void k_replayA(const float2* __restrict__ rlogA,
                                                 double* __restrict__ Q) {
  __shared__ double vr[CH];
  int row = blockIdx.x, t = threadIdx.x;
  const int NR = SW32 * CH;
  for (int j = t; j < CH; j += 128) vr[j] = (j == row) ? 1.0 : 0.0;
  bool act = (t < 95);
  float2 nb[4];
  #pragma unroll
  for (int u = 0; u < 4; ++u)
    nb[u] = (act && u < NR) ? rlogA[(size_t)u * 95 + t] : make_float2(1.f, 0.f);
  BAR_LGKM();
  int r = 0;
  for (int g = 0; g < NR; g += 4) {
    #pragma unroll
    for (int u = 0; u < 4; ++u) {
      float2 cur = nb[u];
      int gn = g + u + 4;
      nb[u] = (act && gn < NR) ? rlogA[(size_t)gn * 95 + t] : make_float2(1.f, 0.f);
      if (act && cur.y != 0.f) {
        int k = t + 1;
        int p = r + k; if (p >= CH) p -= CH;
        int q = r - k; if (q < 0) q += CH;
        double s = (double)cur.y;
        double c = sqrt(fmax(0.0, 1.0 - s * s));   // c >= 0.707 always (|t|<=1)
        double vp = vr[p], vq = vr[q];
        vr[p] = c * vp - s * vq;
        vr[q] = s * vp + c * vq;
      }
      if (++r == CH) r = 0;
      BAR_LGKM();
    }
  }
  for (int j = t; j < CH; j += 128) Q[(size_t)row * CH + j] = vr[j];
}

// ---------------- A' = Q^T G Q (fp64, exact repair of fp32 stage) ---------
__global__ void k_gq(const double* __restrict__ G64, const double* __restrict__ Q,
                     double* __restrict__ T) {
  int j = blockIdx.x * 16 + threadIdx.x, i = blockIdx.y * 16 + threadIdx.y;
  if (i >= CH || j >= CH) return;
  double acc = 0;
  for (int k = 0; k < CH; ++k) acc += G64[i * CH + k] * Q[(size_t)k * CH + j];
  T[i * CH + j] = acc;
}
__global__ void k_qtq(const double* __restrict__ Q, const double* __restrict__ T,
                      double* __restrict__ A2p) {
  int j = blockIdx.x * 16 + threadIdx.x, i = blockIdx.y * 16 + threadIdx.y;
  if (i >= CH || j >= CH || j < i) return;
  double acc = 0;
  for (int k = 0; k < CH; ++k) acc += Q[(size_t)k * CH + i] * T[k * CH + j];
  A2p[pidx(i, j)] = acc;
}

// ---------------- stage D: fp64 polish Jacobi (exactly 1 sweep) -----------
__device__ __forceinline__ int Ftri(int j) {
  return 95 * (j - 1) - ((j * (j - 1)) >> 1);
}
__global__ __launch_bounds__(1024) void k_jac64(const double* __restrict__ A2p,
                                                double* __restrict__ eig,
                                                double2* __restrict__ rlogB) {
  extern __shared__ char smemraw[];
  double* Ap = (double*)smemraw;     // 18336
  double* cs = Ap + NPACK;           // 96
  double* sn = cs + 96;              // 96
  int* ps = (int*)(sn + 96);         // 96
  int* qs = ps + 96;                 // 96
  int t = threadIdx.x;

  int code[5]; int ntask = 0;
  for (int task = t; task < 4560; task += 1024) {
    int cde;
    if (task < 4465) {
      int j = (int)((191.0 - sqrt(35721.0 - 8.0 * (double)task)) * 0.5);
      if (j < 1) j = 1;
      while (j < 94 && Ftri(j + 1) <= task) ++j;
      while (j > 1 && Ftri(j) > task) --j;
      int k = j + 1 + (task - Ftri(j));
      cde = (j << 8) | k;
    } else {
      cde = (1 << 20) | (task - 4465 + 1);
    }
    code[ntask++] = cde;
  }

  for (int e = t; e < NPACK; e += 1024) Ap[e] = A2p[e];
  __syncthreads();

  for (int r = 0; r < CH; ++r) {
    if (t >= 1 && t < 96) {
      int k = t;
      int p = r + k; if (p >= CH) p -= CH;
      int q = r + CH - k; if (q >= CH) q -= CH;
      if (p > q) { int tmp = p; p = q; q = tmp; }
      int ipp = pidx(p, p), ipq = pidx(p, q), iqq = pidx(q, q);
      double app = Ap[ipp], apq = Ap[ipq], aqq = Ap[iqq];
      double c = 1.0, s = 0.0;
      if (fabs(apq) > 4e-16 * (fabs(app) + fabs(aqq)) + 1e-300) {
        double tau = (aqq - app) / (2.0 * apq);
        double tt = copysign(1.0, tau) / (fabs(tau) + sqrt(1.0 + tau * tau));
        c = 1.0 / sqrt(1.0 + tt * tt); s = tt * c;
        Ap[ipp] = app - tt * apq;
        Ap[iqq] = aqq + tt * apq;
        Ap[ipq] = 0.0;
      }
      cs[k] = c; sn[k] = s; ps[k] = p; qs[k] = q;
      rlogB[(size_t)r * 95 + (k - 1)] = make_double2(c, s);
    }
    BAR_LGKM();
    int a0 = r;
    #pragma unroll
    for (int ii = 0; ii < 5; ++ii) {
      if (ii < ntask) {
        int cde = code[ii];
        if (cde & (1 << 20)) {
          int k = cde & 0xff;
          double s = sn[k];
          if (s != 0.0) {
            double c = cs[k];
            int iap = pidxu(a0, ps[k]), iaq = pidxu(a0, qs[k]);
            double vp = Ap[iap], vq = Ap[iaq];
            Ap[iap] = c * vp - s * vq;
            Ap[iaq] = s * vp + c * vq;
          }
        } else {
          int j = (cde >> 8) & 0xff, k = cde & 0xff;
          double sj = sn[j], sk_ = sn[k];
          if (sj != 0.0 || sk_ != 0.0) {
            double cj = cs[j], ck = cs[k];
            int pj = ps[j], qj = qs[j], pk = ps[k], qk = qs[k];
            int i00 = pidxu(pj, pk), i01 = pidxu(pj, qk);
            int i10 = pidxu(qj, pk), i11 = pidxu(qj, qk);
            double m00 = Ap[i00], m01 = Ap[i01], m10 = Ap[i10], m11 = Ap[i11];
            double n00 = ck * m00 - sk_ * m01, n01 = sk_ * m00 + ck * m01;
            double n10 = ck * m10 - sk_ * m11, n11 = sk_ * m10 + ck * m11;
            Ap[i00] = cj * n00 - sj * n10;
            Ap[i10] = sj * n00 + cj * n10;
            Ap[i01] = cj * n01 - sj * n11;
            Ap[i11] = sj * n01 + cj * n11;
          }
        }
      }
    }
    BAR_LGKM();
  }
  for (int i = t; i < CH; i += 1024) eig[i] = Ap[pidx(i, i)];
}

// ---------------- apply stage-D rotations to Q rows -> V ------------------
__global__ __launch_bounds__(128) void k_replayB(const double2* __restrict__ rlogB,
                                                 const double* __restrict__ Q,
                                                 double* __restrict__ V) {
  __shared__ double vr[CH];
  int row = blockIdx.x, t = threadIdx.x;
  const int NR = CH;                 // exactly one polish sweep
  for (int j = t; j < CH; j += 128) vr[j] = Q[(size_t)row * CH + j];
  double2 nxt = (t < 95) ? rlogB[t] : make_double2(1.0, 0.0);
  BAR_LGKM();
  for (int g = 0; g < NR; ++g) {
    double2 cur = nxt;
    if (t < 95 && g + 1 < NR) nxt = rlogB[(size_t)(g + 1) * 95 + t];
    if (t < 95 && cur.y != 0.0) {
      int r = g;
      int k = t + 1;
      int p = r + k; if (p >= CH) p -= CH;
      int q = r + CH - k; if (q >= CH) q -= CH;
      if (p > q) { int tmp = p; p = q; q = tmp; }
      double vp = vr[p], vq = vr[q];
      vr[p] = cur.x * vp - cur.y * vq;
      vr[q] = cur.y * vp + cur.x * vq;
    }
    BAR_LGKM();
  }
  for (int j = t; j < CH; j += 128) V[(size_t)row * CH + j] = vr[j];
}

// ---------------- sort eigenpairs (desc) + whitened eigvec matrix ---------
__global__ __launch_bounds__(256) void k_sortprep(const double* __restrict__ eig,
                                                  const double* __restrict__ V,
                                                  const double* __restrict__ invs,
                                                  int* __restrict__ perm,
                                                  float* __restrict__ Vw) {
  __shared__ double ev[CH];
  __shared__ int pm[CH];
  int t = threadIdx.x;
  if (t < CH) ev[t] = eig[t];
  __syncthreads();
  if (t < CH) {
    double my = ev[t];
    int rk = 0;
    for (int j = 0; j < CH; ++j) {
      double o = ev[j];
      rk += (o > my || (o == my && j < t)) ? 1 : 0;
    }
    pm[rk] = t;
  }
  __syncthreads();
  if (t < CH) perm[t] = pm[t];
  for (int e = t; e < 192 * 192; e += 256) {
    int k = e / 192, i = e - k * 192;
    float v = 0.f;
    if (k < CH && i < CH) v = (float)(invs[k] * V[(size_t)k * CH + pm[i]]);
    Vw[e] = v;
  }
}

// ---------------- pcT = (Y V)^T : [CH][NPIX] ----------------
__global__ __launch_bounds__(256) void k_pc(const float* __restrict__ x,
                                            const float* __restrict__ Vw,
                                            float* __restrict__ pcT) {
  __shared__ float xs[16][65];
  __shared__ float vs[16][33];
  int n0 = blockIdx.x * 64, i0 = blockIdx.y * 32;
  int t = threadIdx.x;
  int tn = t & 15, ti = t >> 4;
  float acc[4][2] = {};
  for (int k0 = 0; k0 < 192; k0 += 16) {
    {
      int col = t & 15, row = t >> 4;
      #pragma unroll
      for (int rr = 0; rr < 4; ++rr) {
        int nn = row + rr * 16;
        int k = k0 + col;
        xs[col][nn] = (k < CH) ? x[(size_t)(n0 + nn) * CH + k] : 0.f;
      }
    }
    {
      int ii = t & 31, kk = t >> 5;
      vs[kk][ii] = Vw[(k0 + kk) * 192 + i0 + ii];
      vs[kk + 8][ii] = Vw[(k0 + kk + 8) * 192 + i0 + ii];
    }
    __syncthreads();
    #pragma unroll
    for (int kk = 0; kk < 16; ++kk) {
      float b0 = vs[kk][ti], b1 = vs[kk][ti + 16];
      #pragma unroll
      for (int rr = 0; rr < 4; ++rr) {
        float a = xs[kk][tn + rr * 16];
        acc[rr][0] += a * b0;
        acc[rr][1] += a * b1;
      }
    }
    __syncthreads();
  }
  #pragma unroll
  for (int rr = 0; rr < 4; ++rr)
    #pragma unroll
    for (int bb = 0; bb < 2; ++bb) {
      int i = i0 + ti + bb * 16, n = n0 + tn + rr * 16;
      if (i < CH) pcT[(size_t)i * NPIX + n] = acc[rr][bb];
    }
}

// ---------------- DWT row pass ----------------
__global__ __launch_bounds__(256) void k_row(const float* __restrict__ in,
                                             float* __restrict__ rb,
                                             int h, int w, int wd, int chS) {
  __shared__ float rowv[256];
  int bid = blockIdx.x;
  int c = bid / h, y = bid % h;
  const float* src = in + (size_t)c * chS + (size_t)y * w;
  int t = threadIdx.x;
  if (t < w) rowv[t] = src[t];
  __syncthreads();
  float* dst = rb + (size_t)(c * h + y) * (2 * wd);
  for (int o = t; o < 2 * wd; o += 256) {
    int b = (o >= wd) ? 1 : 0;
    int xp = b ? o - wd : o;
    float acc = 0.f;
    #pragma unroll
    for (int s = 0; s < 10; ++s) {
      int m = 2 * xp + 1 - s;
      if (m < 0) m = -1 - m;
      else if (m >= w) m = 2 * w - 1 - m;
      acc += (b ? g_dhi[s] : g_dlo[s]) * rowv[m];
    }
    dst[o] = acc;
  }
}

// ---------------- DWT column pass: LL out + high bands to coeff -----------
__global__ __launch_bounds__(256) void k_col(const float* __restrict__ rb,
                                             float* __restrict__ llout,
                                             float* __restrict__ coeff,
                                             int h, int wd, int hd, int chSout,
                                             int offHi, int offLL, int lastlvl) {
  int c = blockIdx.z, yp = blockIdx.y;
  int xq = blockIdx.x * 256 + threadIdx.x;
  if (xq >= 2 * wd) return;
  const float* base = rb + (size_t)c * h * 2 * wd + xq;
  float lo = 0.f, hi = 0.f;
  #pragma unroll
  for (int s = 0; s < 10; ++s) {
    int m = 2 * yp + 1 - s;
    if (m < 0) m = -1 - m;
    else if (m >= h) m = 2 * h - 1 - m;
    float v = base[(size_t)m * 2 * wd];
    lo += g_dlo[s] * v;
    hi += g_dhi[s] * v;
  }
  float* cc = coeff + (size_t)c * CSTRIDE;
  if (xq < wd) {
    llout[(size_t)c * chSout + (size_t)yp * wd + xq] = lo;
    if (lastlvl) cc[offLL + yp * wd + xq] = lo;
    cc[offHi + 0 * hd * wd + yp * wd + xq] = hi;
  } else {
    int xp = xq - wd;
    cc[offHi + 1 * hd * wd + yp * wd + xp] = lo;
    cc[offHi + 2 * hd * wd + yp * wd + xp] = hi;
  }
}

// ---------------- SURE statistics (per-thread accumulate, then reduce) ----
__global__ __launch_bounds__(256) void k_stats(const float* __restrict__ coeff,
                                               double* __restrict__ stats, TArgs ta) {
  int c = blockIdx.y;
  const float* cc = coeff + (size_t)c * CSTRIDE;
  double sm[15], cnt[15], nrm = 0;
  #pragma unroll
  for (int q = 0; q < 15; ++q) { sm[q] = 0; cnt[q] = 0; }
  for (int idx = blockIdx.x * 256 + threadIdx.x; idx < MCOEF; idx += 24 * 256) {
    double v = (double)cc[idx];
    double v2 = v * v;
    nrm += v2;
    #pragma unroll
    for (int q = 0; q < 15; ++q) {
      sm[q] += fmin(v2, ta.t2[q]);
      cnt[q] += (v2 >= ta.t2[q]) ? 1.0 : 0.0;
    }
  }
  __shared__ double wred[4][31];
  int lane = threadIdx.x & 63, wv = threadIdx.x >> 6;
  for (int q = 0; q < 31; ++q) {
    double val = (q < 15) ? sm[q] : ((q < 30) ? cnt[q - 15] : nrm);
    #pragma unroll
    for (int o = 32; o > 0; o >>= 1) val += __shfl_down(val, o);
    if (lane == 0) wred[wv][q] = val;
  }
  __syncthreads();
  if (threadIdx.x < 31) {
    double sum = wred[0][threadIdx.x] + wred[1][threadIdx.x] +
                 wred[2][threadIdx.x] + wred[3][threadIdx.x];
    atomicAdd(&stats[c * 31 + threadIdx.x], sum);
  }
}

// ---------------- SURE scan + rank + masked projection matrix -------------
__global__ __launch_bounds__(256) void k_sure(const double* __restrict__ stats,
                                              const double* __restrict__ sqrtom,
                                              const double* __restrict__ V,
                                              const int* __restrict__ perm,
                                              const int* __restrict__ min_iter_p,
                                              float* __restrict__ Wm,
                                              int* __restrict__ meta) {
  __shared__ double st[CH * 31];
  __shared__ double minsure[CH];
  __shared__ int rankS;
  int t = threadIdx.x;
  for (int e = t; e < CH * 31; e += 256) st[e] = stats[e];
  __syncthreads();
  if (t == 0) {
    double norm2 = 0;
    for (int c = 0; c < CH; ++c) norm2 += st[c * 31 + 30];
    double K = norm2 - (double)MCOEF * (double)CH;
    double cum[15];
    for (int q = 0; q < 15; ++q) cum[q] = 0;
    for (int r = 0; r < CH; ++r) {
      double mn = 1e300;
      for (int q = 0; q < 15; ++q) {
        double sure = st[r * 31 + q] + 2.0 * st[r * 31 + 15 + q] - (double)MCOEF;
        double s = cum[q] + sure + K;
        cum[q] += s;
        if (s < mn) mn = s;
      }
      minsure[r] = mn;
    }
    int mi = *min_iter_p;
    int rank = CH - 1;
    for (int r = 0; r < CH; ++r) {
      double prev = (r == 0) ? minsure[0] : minsure[r - 1];
      bool cond = (r > mi) && !(minsure[r] > 2.0 * prev);
      if (cond) { rank = r; break; }
    }
    rankS = rank;
    meta[1] = rank;
  }
  __syncthreads();
  int rank = rankS;
  for (int e = t; e < 192 * 192; e += 256) {
    int k = e / 192, c = e - k * 192;
    float v = 0.f;
    if (k < rank && c < CH) v = (float)(sqrtom[c] * V[(size_t)c * CH + perm[k]]);
    Wm[e] = v;
  }
}

// ---------------- out = pcT^T * Wm ----------------
__global__ __launch_bounds__(256) void k_out(const float* __restrict__ pcT,
                                             const float* __restrict__ Wm,
                                             float* __restrict__ out) {
  __shared__ float psx[16][65];
  __shared__ float wsx[16][33];
  int n0 = blockIdx.x * 64, c0 = blockIdx.y * 32;
  int t = threadIdx.x;
  int tc = t & 15, tn = t >> 4;
  float acc[4][2] = {};
  for (int k0 = 0; k0 < 192; k0 += 16) {
    {
      int nn = t & 63, kk0 = t >> 6;
      #pragma unroll
      for (int rr = 0; rr < 4; ++rr) {
        int kk = kk0 + rr * 4;
        int k = k0 + kk;
        psx[kk][nn] = (k < CH) ? pcT[(size_t)k * NPIX + n0 + nn] : 0.f;
      }
    }
    {
      int cc = t & 31, kk = t >> 5;
      wsx[kk][cc] = Wm[(k0 + kk) * 192 + c0 + cc];
      wsx[kk + 8][cc] = Wm[(k0 + kk + 8) * 192 + c0 + cc];
    }
    __syncthreads();
    #pragma unroll
    for (int kk = 0; kk < 16; ++kk) {
      float b0 = wsx[kk][tc], b1 = wsx[kk][tc + 16];
      #pragma unroll
      for (int rr = 0; rr < 4; ++rr) {
        float a = psx[kk][tn + rr * 16];
        acc[rr][0] += a * b0;
        acc[rr][1] += a * b1;
      }
    }
    __syncthreads();
  }
  #pragma unroll
  for (int rr = 0; rr < 4; ++rr)
    #pragma unroll
    for (int bb = 0; bb < 2; ++bb) {
      int n = n0 + tn + rr * 16, c = c0 + tc + bb * 16;
      if (c < CH) out[(size_t)n * CH + c] = acc[rr][bb];
    }
}

// ---------------- host ----------------
extern "C" void kernel_launch(void* const* d_in, const int* in_sizes, int n_in,
                              void* d_out, int out_size, void* d_ws, size_t ws_size,
                              hipStream_t stream) {
  const float* x = (const float*)d_in[0];
  const int* p_min_iter = (const int*)d_in[1];
  float* out = (float*)d_out;
  char* ws = (char*)d_ws;

  size_t cur = 0;
  auto A = [&](size_t b) { size_t o = cur; cur += (b + 511) & ~(size_t)511; return o; };
  double* ddp     = (double*)(ws + A((size_t)CH * CH * 8));
  double* ddpi64  = (double*)(ws + A((size_t)CH * CH * 8));
  double* Tm      = (double*)(ws + A((size_t)CH * CH * 8));
  double* V       = (double*)(ws + A((size_t)CH * CH * 8));
  double* G64     = (double*)(ws + A((size_t)CH * CH * 8));
  double* T64     = (double*)(ws + A((size_t)CH * CH * 8));
  double* Q       = (double*)(ws + A((size_t)CH * CH * 8));
  double* A2p     = (double*)(ws + A((size_t)NPACK * 8));
  double* eig     = (double*)(ws + A((size_t)CH * 8));
  double* rsum    = (double*)(ws + A((size_t)CH * 8));
  double* sqrtom  = (double*)(ws + A((size_t)CH * 8));
  double* invs    = (double*)(ws + A((size_t)CH * 8));
  double* stats   = (double*)(ws + A((size_t)CH * 31 * 8));
  int* perm       = (int*)(ws + A((size_t)CH * 4));
  int* meta       = (int*)(ws + A(64));
  float* ddpi32   = (float*)(ws + A((size_t)CH * CH * 4));
  float* Gsk      = (float*)(ws + A((size_t)NSKEW * 4));
  float* dgf      = (float*)(ws + A((size_t)CH * 4));
  float* Vw       = (float*)(ws + A((size_t)192 * 192 * 4));
  float* Wm       = (float*)(ws + A((size_t)192 * 192 * 4));
  float2* rlogA   = (float2*)(ws + A((size_t)SW32 * CH * 95 * 8));
  double2* rlogB  = (double2*)(ws + A((size_t)CH * 95 * 16));
  float* pcT      = (float*)(ws + A((size_t)CH * NPIX * 4));
  float* rowbuf   = (float*)(ws + A((size_t)CH * 256 * 264 * 4));
  float* llA      = (float*)(ws + A((size_t)CH * 17424 * 4));
  float* llB      = (float*)(ws + A((size_t)CH * 4900 * 4));
  float* coeff    = (float*)(ws + A((size_t)CH * CSTRIDE * 4));
  (void)ws_size; (void)in_sizes; (void)n_in; (void)out_size;

  hipMemsetAsync(ddp, 0, (size_t)CH * CH * 8, stream);
  hipMemsetAsync(rsum, 0, (size_t)CH * 8, stream);
  hipMemsetAsync(stats, 0, (size_t)CH * 31 * 8, stream);

  const int GJ_SMEM = (CH * CH + CH) * 4;                       // 146688
  const int J32_SMEM = NSKEW * 4;                               // 74496
  const int J64_SMEM = (NPACK + 96 + 96) * 8 + (96 + 96) * 4 + 256;

  k_ddp<<<dim3(6, 6, 16), 256, 0, stream>>>(x, ddp);
  k_mirror<<<143, 256, 0, stream>>>(ddp);
  k_rsum<<<256, 256, 0, stream>>>(x, rsum);
  (void)hipFuncSetAttribute((const void*)k_gj,
        hipFuncAttributeMaxDynamicSharedMemorySize, GJ_SMEM);
  k_gj<<<1, 1024, GJ_SMEM, stream>>>(ddp, ddpi32);
  k_newton1<<<dim3(12, 12), dim3(16, 16), 0, stream>>>(ddp, ddpi32, Tm);
  k_newton2<<<dim3(12, 12), dim3(16, 16), 0, stream>>>(ddpi32, Tm, ddpi64);
  k_beta<<<CH, 256, 0, stream>>>(ddp, ddpi64, rsum, sqrtom, invs);
  k_packG<<<143, 256, 0, stream>>>(ddp, invs, Gsk, dgf, G64);
  (void)hipFuncSetAttribute((const void*)k_jac32,
        hipFuncAttributeMaxDynamicSharedMemorySize, J32_SMEM);
  k_jac32<<<1, 1024, J32_SMEM, stream>>>(Gsk, dgf, rlogA);
  k_replayA<<<CH, 128, 0, stream>>>(rlogA, Q);
  k_gq<<<dim3(12, 12), dim3(16, 16), 0, stream>>>(G64, Q, T64);
  k_qtq<<<dim3(12, 12), dim3(16, 16), 0, stream>>>(Q, T64, A2p);
  (void)hipFuncSetAttribute((const void*)k_jac64,
        hipFuncAttributeMaxDynamicSharedMemorySize, J64_SMEM);
  k_jac64<<<1, 1024, J64_SMEM, stream>>>(A2p, eig, rlogB);
  k_replayB<<<CH, 128, 0, stream>>>(rlogB, Q, V);
  k_sortprep<<<1, 256, 0, stream>>>(eig, V, invs, perm, Vw);
  k_pc<<<dim3(1024, 6), 256, 0, stream>>>(x, Vw, pcT);

  int hs[6] = {256, 132, 70, 39, 24, 16};
  int offHi[5];
  { int a0 = 0; for (int l = 0; l < 5; ++l) { offHi[l] = a0; a0 += 3 * hs[l + 1] * hs[l + 1]; } }
  const int offLL = 74031;
  float* lls[6] = {pcT, llA, llB, llA, llB, llA};
  for (int l = 0; l < 5; ++l) {
    int h = hs[l], w = hs[l], wd = hs[l + 1], hd = hs[l + 1];
    k_row<<<CH * h, 256, 0, stream>>>(lls[l], rowbuf, h, w, wd, h * w);
    k_col<<<dim3((2 * wd + 255) / 256, hd, CH), 256, 0, stream>>>(
        rowbuf, lls[l + 1], coeff, h, wd, hd, hd * wd, offHi[l], offLL,
        (l == 4) ? 1 : 0);
  }

  TArgs ta;
  {
    double tmax = sqrt(log((double)MCOEF));
    for (int j = 0; j < 15; ++j) { double tv = tmax * j / 14.0; ta.t2[j] = tv * tv; }
  }
  k_stats<<<dim3(24, CH), 256, 0, stream>>>(coeff, stats, ta);
  k_sure<<<1, 256, 0, stream>>>(stats, sqrtom, V, perm, p_min_iter, Wm, meta);
  k_out<<<dim3(1024, 6), 256, 0, stream>>>(pcT, Wm, out);
}

// Round 7
// 5009.221 us; speedup vs baseline: 1.2282x; 1.1058x over previous
//
#include <hip/hip_runtime.h>
#include <math.h>
#include <cstdint>

// ---------------- constants ----------------
#define CH 191
#define NPIX 65536
#define MCOEF 74287            // total wavelet coeffs per channel
#define CSTRIDE 74288
#define SW32 6                 // fp32 Jacobi sweeps (8->7->6: fp64 repair absorbs;
                               // absmax floor is set by fp32 GEMM paths, not Jacobi)
// (fold(a-b), (a+b) mod 191) layout: addr = df*194 + s, df in [0,95], s in [0,191)
// row stride 194: lane strides of phase-2 element runs are +-194+-1 -> +-1/+-3 mod 32
#define NSKEW (96 * 194)       // 18624 elements

__device__ const float g_dlo[10] = {
  0.003335725285001549f, -0.012580751999015526f, -0.006241490213011705f,
  0.07757149384006515f, -0.03224486958502952f, -0.24229488706619015f,
  0.13842814590110342f, 0.7243085284385744f, 0.6038292697974729f,
  0.160102397974125f };
__device__ const float g_dhi[10] = {
  -0.160102397974125f, 0.6038292697974729f, -0.7243085284385744f,
  0.13842814590110342f, 0.24229488706619015f, -0.03224486958502952f,
  -0.07757149384006515f, -0.006241490213011705f, 0.012580751999015526f,
  0.003335725285001549f };

struct TArgs { double t2[15]; };

// bijective address for unordered pair {a,b}: s=(a+b)%191, df=min(|a-b|,191-|a-b|)
__device__ __forceinline__ int sk(int a, int b) {
  int s = a + b; if (s >= CH) s -= CH;
  int d = a - b; if (d < 0) d = -d;
  int df = (d > 95) ? (CH - d) : d;
  return df * 194 + s;
}

// lgkm-only barrier: per-wave LDS ops drained before signaling; never waits vmcnt,
// so fire-and-forget global stores (rotation logs) don't stall the step loop.
#define BAR_LGKM() asm volatile("s_waitcnt lgkmcnt(0)\n\ts_barrier" ::: "memory")

// ---------------- ddp = X^T X (fp64 accum) ----------------
__global__ __launch_bounds__(256) void k_ddp(const float* __restrict__ x,
                                             double* __restrict__ ddp) {
  __shared__ float as[32][33];
  __shared__ float bs[32][33];
  int i0 = blockIdx.x * 32, j0 = blockIdx.y * 32;
  if (j0 < i0) return;                       // upper tiles only; mirrored later
  int t = threadIdx.x;
  int n0 = blockIdx.z * 4096;
  int tx = t & 15, ty = t >> 4;
  double a00 = 0, a01 = 0, a10 = 0, a11 = 0;
  for (int nb = 0; nb < 4096; nb += 32) {
    for (int e = t; e < 1024; e += 256) {
      int kk = e >> 5, ii = e & 31;
      int n = n0 + nb + kk;
      as[kk][ii] = (i0 + ii < CH) ? x[(size_t)n * CH + i0 + ii] : 0.f;
      bs[kk][ii] = (j0 + ii < CH) ? x[(size_t)n * CH + j0 + ii] : 0.f;
    }
    __syncthreads();
    #pragma unroll 8
    for (int kk = 0; kk < 32; ++kk) {
      double x0 = as[kk][tx], x1 = as[kk][tx + 16];
      double y0 = bs[kk][ty], y1 = bs[kk][ty + 16];
      a00 += x0 * y0; a01 += x0 * y1; a10 += x1 * y0; a11 += x1 * y1;
    }
    __syncthreads();
  }
  int i = i0 + tx, j = j0 + ty;
  if (i < CH) {
    if (j < CH)      atomicAdd(&ddp[i * CH + j], a00);
    if (j + 16 < CH) atomicAdd(&ddp[i * CH + j + 16], a01);
  }
  if (i + 16 < CH) {
    if (j < CH)      atomicAdd(&ddp[(i + 16) * CH + j], a10);
    if (j + 16 < CH) atomicAdd(&ddp[(i + 16) * CH + j + 16], a11);
  }
}

__global__ void k_mirror(double* __restrict__ ddp) {
  int e = blockIdx.x * 256 + threadIdx.x;
  if (e >= CH * CH) return;
  int i = e / CH, j = e % CH;
  if (i > j) ddp[e] = ddp[j * CH + i];
}

__global__ __launch_bounds__(256) void k_rsum(const float* __restrict__ x,
                                              double* __restrict__ rsum) {
  int t = threadIdx.x;
  if (t >= CH) return;
  int row0 = blockIdx.x * 256;
  double a = 0;
  for (int r = 0; r < 256; ++r) a += (double)x[(size_t)(row0 + r) * CH + t];
  atomicAdd(&rsum[t], a);
}

// ---------------- Gauss-Jordan inverse (fp32, in LDS) ----------------
__global__ __launch_bounds__(1024) void k_gj(const double* __restrict__ ddp,
                                             float* __restrict__ out) {
  extern __shared__ char smemraw[];
  float* A = (float*)smemraw;
  float* fc = A + CH * CH;
  int t = threadIdx.x;
  for (int e = t; e < CH * CH; e += 1024) {
    int i = e / CH, j = e % CH;
    A[e] = (float)(ddp[e] + (i == j ? 1e-6 : 0.0));
  }
  __syncthreads();
  for (int k = 0; k < CH; ++k) {
    float pivinv = 1.0f / A[k * CH + k];
    for (int i = t; i < CH; i += 1024) fc[i] = A[i * CH + k];
    __syncthreads();
    for (int j = t; j < CH; j += 1024)
      A[k * CH + j] = (j == k ? 1.0f : A[k * CH + j]) * pivinv;
    __syncthreads();
    for (int e = t; e < CH * CH; e += 1024) {
      int i = e / CH, j = e % CH;
      if (i != k) A[e] = (j == k ? 0.0f : A[e]) - A[k * CH + j] * fc[i];
    }
    __syncthreads();
  }
  for (int e = t; e < CH * CH; e += 1024) out[e] = A[e];
}

// ---------------- one Newton refinement step: P = X(2I - A X), fp64 -------
__global__ void k_newton1(const double* __restrict__ ddp, const float* __restrict__ X,
                          double* __restrict__ T) {
  int j = blockIdx.x * 16 + threadIdx.x, i = blockIdx.y * 16 + threadIdx.y;
  if (i >= CH || j >= CH) return;
  double acc = 0;
  for (int k = 0; k < CH; ++k) {
    double a = ddp[i * CH + k] + (i == k ? 1e-6 : 0.0);
    acc += a * (double)X[k * CH + j];
  }
  T[i * CH + j] = (i == j ? 2.0 : 0.0) - acc;
}
__global__ void k_newton2(const float* __restrict__ X, const double* __restrict__ T,
                          double* __restrict__ P) {
  int j = blockIdx.x * 16 + threadIdx.x, i = blockIdx.y * 16 + threadIdx.y;
  if (i >= CH || j >= CH) return;
  double acc = 0;
  for (int k = 0; k < CH; ++k) acc += (double)X[i * CH + k] * T[k * CH + j];
  P[i * CH + j] = acc;
}

// ---------------- per-band regression -> omega ----------------
__global__ __launch_bounds__(256) void k_beta(const double* __restrict__ ddp,
                                              const double* __restrict__ P,
                                              const double* __restrict__ rsum,
                                              double* __restrict__ sqrtom,
                                              double* __restrict__ invs) {
  __shared__ double bet[CH];
  __shared__ double red[256];
  int i = blockIdx.x, t = threadIdx.x;
  double pii = P[i * CH + i];
  for (int j = t; j < CH; j += 256) {
    double pjip = P[j * CH + i] / pii;
    double acc = 0;
    for (int k = 0; k < CH; ++k) {
      double ddpa = (k == i) ? 0.0 : ddp[k * CH + i];
      acc += (P[j * CH + k] - pjip * P[i * CH + k]) * ddpa;
    }
    bet[j] = (j == i) ? 0.0 : acc;
  }
  __syncthreads();
  double s1 = 0, s2 = 0;
  for (int j = t; j < CH; j += 256) {
    double gj = ((j == i) ? 1.0 : 0.0) - bet[j];
    s1 += gj * rsum[j];
    double tj = 0;
    for (int k = 0; k < CH; ++k) {
      double gk = ((k == i) ? 1.0 : 0.0) - bet[k];
      tj += ddp[j * CH + k] * gk;
    }
    s2 += gj * tj;
  }
  red[t] = s1; __syncthreads();
  for (int o = 128; o; o >>= 1) { if (t < o) red[t] += red[t + o]; __syncthreads(); }
  double sumw = red[0]; __syncthreads();
  red[t] = s2; __syncthreads();
  for (int o = 128; o; o >>= 1) { if (t < o) red[t] += red[t + o]; __syncthreads(); }
  if (t == 0) {
    double sumsq = red[0];
    double var = (sumsq - sumw * sumw / 65536.0) / 65535.0;
    if (var < 0) var = 0;
    double so = sqrt(var) + 1e-30;
    sqrtom[i] = so;
    invs[i] = 1.0 / so;
  }
}

// ---------------- whitened Gram: (df,s)-layout fp32 + diag + full fp64 -----
__global__ void k_packG(const double* __restrict__ ddp, const double* __restrict__ invs,
                        float* __restrict__ Gsk, float* __restrict__ dgf,
                        double* __restrict__ G64) {
  int e = blockIdx.x * 256 + threadIdx.x;
  if (e >= CH * CH) return;
  int i = e / CH, j = e % CH;
  double v = ddp[e] * invs[i] * invs[j];
  G64[e] = v;
  if (j >= i) Gsk[sk(i, j)] = (float)v;
  if (j == i) dgf[i] = (float)v;
}

// ---------------- stage A: single-block fp32 Jacobi (two-phase, R4 struct) --
// Proven structure: loads hoisted before phase-1, two lgkm barriers/step.
// Diagonals live in dg[CH] (phase-1 reads lane-consecutive, conflict-free;
// As holds off-diag only). The 4 element addresses per task are INCREMENTAL
// byte addresses: s advances by +2 mod 191 per step => addr += 8 bytes, wrap
// (-=764) when crossing row base + 191*4.
__global__ __launch_bounds__(1024) void k_jac32(const float* __restrict__ Gsk,
                                                const float* __restrict__ dg0,
                                                float2* __restrict__ rlogA) {
  extern __shared__ float As[];        // NSKEW floats, (df,s) layout
  __shared__ float2 csn[96];
  __shared__ float dg[CH];
  int t = threadIdx.x;

  int jS[5], kS[5]; int ntask = 0;
  for (int id = t; id < 4560; id += 1024) {
    int j = 0, off = 0;
    while (off + (95 - j) <= id) { off += 95 - j; ++j; }
    jS[ntask] = j; kS[ntask] = j + 1 + (id - off);
    ++ntask;
  }
  // incremental byte addresses, initialized for r=0 (s2r = 0)
  int a00[5], a01[5], a10[5], a11[5], limA[5], limB[5];
  #pragma unroll
  for (int ii = 0; ii < 5; ++ii) {
    if (ii < ntask) {
      int j = jS[ii], k = kS[ii];
      int A = j + k;                          // s-offset for (pj,pk)/(qj,qk)
      int B = k - j;                          // s-offset for (pj,qk)/(qj,pk)
      int dfB = (A > 95) ? (CH - A) : A;      // fold(j+k)
      int bA = B * 194;                       // row of (pj,pk)/(qj,qk)
      int bB = dfB * 194;                     // row of (pj,qk)/(qj,pk)
      a00[ii] = (bA + A) * 4;                 // s00 = A    (A in [1,189])
      a11[ii] = (bA + CH - A) * 4;            // s11 = 191-A
      a01[ii] = (bB + CH - B) * 4;            // s01 = 191-B (B in [1,95])
      a10[ii] = (bB + B) * 4;                 // s10 = B
      limA[ii] = (bA + CH) * 4;
      limB[ii] = (bB + CH) * 4;
    } else {
      a00[ii] = a01[ii] = a10[ii] = a11[ii] = 0;
      limA[ii] = limB[ii] = 1 << 30; jS[ii] = 0; kS[ii] = 1;
    }
  }

  for (int e = t; e < NSKEW; e += 1024) As[e] = Gsk[e];
  if (t < CH) dg[t] = dg0[t];
  __syncthreads();

  const char* Asb = (const char*)As;
  for (int sweep = 0; sweep < SW32; ++sweep) {
    for (int r = 0; r < CH; ++r) {
      // ---- pre-barrier: issue this step's element loads (disjoint from
      //      phase-1's pivot/diag set -> race-free; R1-proven) ----
      float m0[5], m1[5], m2[5], m3[5];
      #pragma unroll
      for (int ii = 0; ii < 5; ++ii) {
        if (ii < ntask) {
          m0[ii] = *(const float*)(Asb + a00[ii]);
          m1[ii] = *(const float*)(Asb + a01[ii]);
          if (jS[ii] != 0) {
            m2[ii] = *(const float*)(Asb + a10[ii]);
            m3[ii] = *(const float*)(Asb + a11[ii]);
          }
        }
      }
      // ---- phase 1: rotation generation on lanes 1..95 (waves 0-1 only) ----
      if (t >= 1 && t < 96) {
        int p = r + t; if (p >= CH) p -= CH;
        int q = r - t; if (q < 0) q += CH;
        int ipq = sk(p, q);
        float app = dg[p], aqq = dg[q], apq = As[ipq];
        float c = 1.0f, s = 0.0f, piv = apq, dp = app, dq = aqq;
        if (fabsf(apq) > 3e-7f * (fabsf(app) + fabsf(aqq)) + 1e-30f) {
          float tau = (aqq - app) / (2.0f * apq);
          float tt = copysignf(1.0f, tau) / (fabsf(tau) + sqrtf(1.0f + tau * tau));
          c = 1.0f / sqrtf(1.0f + tt * tt); s = tt * c;
          dp = app - tt * apq; dq = aqq + tt * apq; piv = 0.0f;
        }
        dg[p] = dp; dg[q] = dq;
        As[ipq] = piv;
        csn[t] = make_float2(c, s);
        rlogA[((size_t)(sweep * CH + r)) * 95 + (t - 1)] = make_float2(c, s);
      }
      BAR_LGKM();
      // ---- phase 2: apply rotations (branch-free identity exact) ----
      #pragma unroll
      for (int ii = 0; ii < 5; ++ii) {
        if (ii < ntask) {
          float2 ck2 = csn[kS[ii]];
          if (jS[ii] == 0) {
            float vp = m0[ii], vq = m1[ii];
            *(float*)((char*)As + a00[ii]) = ck2.x * vp - ck2.y * vq;
            *(float*)((char*)As + a01[ii]) = ck2.y * vp + ck2.x * vq;
          } else {
            float2 cj2 = csn[jS[ii]];
            float n00 = ck2.x * m0[ii] - ck2.y * m1[ii];
            float n01 = ck2.y * m0[ii] + ck2.x * m1[ii];
            float n10 = ck2.x * m2[ii] - ck2.y * m3[ii];
            float n11 = ck2.y * m2[ii] + ck2.x * m3[ii];
            *(float*)((char*)As + a00[ii]) = cj2.x * n00 - cj2.y * n10;
            *(float*)((char*)As + a10[ii]) = cj2.y * n00 + cj2.x * n10;
            *(float*)((char*)As + a01[ii]) = cj2.x * n01 - cj2.y * n11;
            *(float*)((char*)As + a11[ii]) = cj2.y * n01 + cj2.x * n11;
          }
          // advance addresses to next step: s += 2 mod 191 => +8B, wrap -764B
          a00[ii] += 8; if (a00[ii] >= limA[ii]) a00[ii] -= 764;
          a11[ii] += 8; if (a11[ii] >= limA[ii]) a11[ii] -= 764;
          a01[ii] += 8; if (a01[ii] >= limB[ii]) a01[ii] -= 764;
          a10[ii] += 8; if (a10[ii] >= limB[ii]) a10[ii] -= 764;
        }
      }
      BAR_LGKM();
    }
  }
}

// ---------------- replay fp32 rotations -> Q (fp64, raw orientation) ------
// 4-deep global prefetch of the rotation log; lgkm-only barriers so the
// prefetch latency spans 4 rounds instead of stalling each round.
// NR need not be a multiple of 4: out-of-range prefetch slots are filled with
// identity (c=1,s=0) and their rotations are no-ops.
__global__ __launch_bounds__(128) void k_replayA(const float2* __restrict__ rlogA,
                                                 double* __restrict__ Q) {
  __shared__ double vr[CH];
  int row = blockIdx.x, t = threadIdx.x;
  const int NR = SW32 * CH;
  for (int j = t; j < CH; j += 128) vr[j] = (j == row) ? 1.0 : 0.0;
  bool act = (t < 95);
  float2 nb[4];
  #pragma unroll
  for (int u = 0; u < 4; ++u)
    nb[u] = (act && u < NR) ? rlogA[(size_t)u * 95 + t] : make_float2(1.f, 0.f);
  BAR_LGKM();
  int r = 0;
  for (int g = 0; g < NR; g += 4) {
    #pragma unroll
    for (int u = 0; u < 4; ++u) {
      float2 cur = nb[u];
      int gn = g + u + 4;
      nb[u] = (act && gn < NR) ? rlogA[(size_t)gn * 95 + t] : make_float2(1.f, 0.f);
      if (act && cur.y != 0.f) {
        int k = t + 1;
        int p = r + k; if (p >= CH) p -= CH;
        int q = r - k; if (q < 0) q += CH;
        double s = (double)cur.y;
        double c = sqrt(fmax(0.0, 1.0 - s * s));   // c >= 0.707 always (|t|<=1)
        double vp = vr[p], vq = vr[q];
        vr[p] = c * vp - s * vq;
        vr[q] = s * vp + c * vq;
      }
      if (++r == CH) r = 0;
      BAR_LGKM();
    }
  }
  for (int j = t; j < CH; j += 128) Q[(size_t)row * CH + j] = vr[j];
}

// ---------------- A' = Q^T G Q (fp64, exact repair of fp32 stage) ---------
__global__ void k_gq(const double* __restrict__ G64, const double* __restrict__ Q,
                     double* __restrict__ T) {
  int j = blockIdx.x * 16 + threadIdx.x, i = blockIdx.y * 16 + threadIdx.y;
  if (i >= CH || j >= CH) return;
  double acc = 0;
  for (int k = 0; k < CH; ++k) acc += G64[i * CH + k] * Q[(size_t)k * CH + j];
  T[i * CH + j] = acc;
}
// outputs in (df,s) layout + separate diagonal array (feeds fp64 Jacobi)
__global__ void k_qtq(const double* __restrict__ Q, const double* __restrict__ T,
                      double* __restrict__ A2sk, double* __restrict__ dg64) {
  int j = blockIdx.x * 16 + threadIdx.x, i = blockIdx.y * 16 + threadIdx.y;
  if (i >= CH || j >= CH || j < i) return;
  double acc = 0;
  for (int k = 0; k < CH; ++k) acc += Q[(size_t)k * CH + i] * T[k * CH + j];
  if (j == i) dg64[i] = acc;
  else A2sk[sk(i, j)] = acc;
}

// ---------------- stage D: fp64 polish Jacobi (exactly 1 sweep) -----------
// fp64 clone of k_jac32's proven structure: (df,s) layout, diagonals in dg[],
// incremental byte addresses (+16B/step, wrap -1528), unswapped (p,q)=(r+t,r-t)
// convention in gen AND replayB. A rotation on (q,p) with (c,-s) is the same
// similarity transform as on (p,q) with (c,s), so the matrix/V sequence is
// numerically identical to the old swapped-pidxu version.
__global__ __launch_bounds__(1024) void k_jac64(const double* __restrict__ A2sk,
                                                const double* __restrict__ dg0,
                                                double* __restrict__ eig,
                                                double2* __restrict__ rlogB) {
  extern __shared__ double As64[];     // NSKEW doubles, (df,s) layout (149 KB)
  __shared__ double2 csn[96];
  __shared__ double dg[CH];
  int t = threadIdx.x;

  int jS[5], kS[5]; int ntask = 0;
  for (int id = t; id < 4560; id += 1024) {
    int j = 0, off = 0;
    while (off + (95 - j) <= id) { off += 95 - j; ++j; }
    jS[ntask] = j; kS[ntask] = j + 1 + (id - off);
    ++ntask;
  }
  int a00[5], a01[5], a10[5], a11[5], limA[5], limB[5];
  #pragma unroll
  for (int ii = 0; ii < 5; ++ii) {
    if (ii < ntask) {
      int j = jS[ii], k = kS[ii];
      int A = j + k;
      int B = k - j;
      int dfB = (A > 95) ? (CH - A) : A;
      int bA = B * 194;
      int bB = dfB * 194;
      a00[ii] = (bA + A) * 8;
      a11[ii] = (bA + CH - A) * 8;
      a01[ii] = (bB + CH - B) * 8;
      a10[ii] = (bB + B) * 8;
      limA[ii] = (bA + CH) * 8;
      limB[ii] = (bB + CH) * 8;
    } else {
      a00[ii] = a01[ii] = a10[ii] = a11[ii] = 0;
      limA[ii] = limB[ii] = 1 << 30; jS[ii] = 0; kS[ii] = 1;
    }
  }

  for (int e = t; e < NSKEW; e += 1024) As64[e] = A2sk[e];
  if (t < CH) dg[t] = dg0[t];
  __syncthreads();

  const char* Asb = (const char*)As64;
  for (int r = 0; r < CH; ++r) {
    double m0[5], m1[5], m2[5], m3[5];
    #pragma unroll
    for (int ii = 0; ii < 5; ++ii) {
      if (ii < ntask) {
        m0[ii] = *(const double*)(Asb + a00[ii]);
        m1[ii] = *(const double*)(Asb + a01[ii]);
        if (jS[ii] != 0) {
          m2[ii] = *(const double*)(Asb + a10[ii]);
          m3[ii] = *(const double*)(Asb + a11[ii]);
        }
      }
    }
    if (t >= 1 && t < 96) {
      int p = r + t; if (p >= CH) p -= CH;
      int q = r - t; if (q < 0) q += CH;
      int ipq = sk(p, q);
      double app = dg[p], aqq = dg[q], apq = As64[ipq];
      double c = 1.0, s = 0.0, piv = apq, dp = app, dq = aqq;
      if (fabs(apq) > 4e-16 * (fabs(app) + fabs(aqq)) + 1e-300) {
        double tau = (aqq - app) / (2.0 * apq);
        double tt = copysign(1.0, tau) / (fabs(tau) + sqrt(1.0 + tau * tau));
        c = 1.0 / sqrt(1.0 + tt * tt); s = tt * c;
        dp = app - tt * apq; dq = aqq + tt * apq; piv = 0.0;
      }
      dg[p] = dp; dg[q] = dq;
      As64[ipq] = piv;
      csn[t] = make_double2(c, s);
      rlogB[(size_t)r * 95 + (t - 1)] = make_double2(c, s);
    }
    BAR_LGKM();
    #pragma unroll
    for (int ii = 0; ii < 5; ++ii) {
      if (ii < ntask) {
        double2 ck2 = csn[kS[ii]];
        if (jS[ii] == 0) {
          double vp = m0[ii], vq = m1[ii];
          *(double*)((char*)As64 + a00[ii]) = ck2.x * vp - ck2.y * vq;
          *(double*)((char*)As64 + a01[ii]) = ck2.y * vp + ck2.x * vq;
        } else {
          double2 cj2 = csn[jS[ii]];
          double n00 = ck2.x * m0[ii] - ck2.y * m1[ii];
          double n01 = ck2.y * m0[ii] + ck2.x * m1[ii];
          double n10 = ck2.x * m2[ii] - ck2.y * m3[ii];
          double n11 = ck2.y * m2[ii] + ck2.x * m3[ii];
          *(double*)((char*)As64 + a00[ii]) = cj2.x * n00 - cj2.y * n10;
          *(double*)((char*)As64 + a10[ii]) = cj2.y * n00 + cj2.x * n10;
          *(double*)((char*)As64 + a01[ii]) = cj2.x * n01 - cj2.y * n11;
          *(double*)((char*)As64 + a11[ii]) = cj2.y * n01 + cj2.x * n11;
        }
        // advance: s += 2 mod 191 => +16B, wrap -1528B
        a00[ii] += 16; if (a00[ii] >= limA[ii]) a00[ii] -= 1528;
        a11[ii] += 16; if (a11[ii] >= limA[ii]) a11[ii] -= 1528;
        a01[ii] += 16; if (a01[ii] >= limB[ii]) a01[ii] -= 1528;
        a10[ii] += 16; if (a10[ii] >= limB[ii]) a10[ii] -= 1528;
      }
    }
    BAR_LGKM();
  }
  for (int i = t; i < CH; i += 1024) eig[i] = dg[i];
}

// ---------------- apply stage-D rotations to Q rows -> V ------------------
// unswapped convention matching k_jac64's gen: (p,q) = (g+k, g-k) mod 191
__global__ __launch_bounds__(128) void k_replayB(const double2* __restrict__ rlogB,
                                                 const double* __restrict__ Q,
                                                 double* __restrict__ V) {
  __shared__ double vr[CH];
  int row = blockIdx.x, t = threadIdx.x;
  const int NR = CH;                 // exactly one polish sweep
  for (int j = t; j < CH; j += 128) vr[j] = Q[(size_t)row * CH + j];
  double2 nxt = (t < 95) ? rlogB[t] : make_double2(1.0, 0.0);
  BAR_LGKM();
  for (int g = 0; g < NR; ++g) {
    double2 cur = nxt;
    if (t < 95 && g + 1 < NR) nxt = rlogB[(size_t)(g + 1) * 95 + t];
    if (t < 95 && cur.y != 0.0) {
      int k = t + 1;
      int p = g + k; if (p >= CH) p -= CH;
      int q = g - k; if (q < 0) q += CH;
      double vp = vr[p], vq = vr[q];
      vr[p] = cur.x * vp - cur.y * vq;
      vr[q] = cur.y * vp + cur.x * vq;
    }
    BAR_LGKM();
  }
  for (int j = t; j < CH; j += 128) V[(size_t)row * CH + j] = vr[j];
}

// ---------------- sort eigenpairs (desc) + whitened eigvec matrix ---------
__global__ __launch_bounds__(256) void k_sortprep(const double* __restrict__ eig,
                                                  const double* __restrict__ V,
                                                  const double* __restrict__ invs,
                                                  int* __restrict__ perm,
                                                  float* __restrict__ Vw) {
  __shared__ double ev[CH];
  __shared__ int pm[CH];
  int t = threadIdx.x;
  if (t < CH) ev[t] = eig[t];
  __syncthreads();
  if (t < CH) {
    double my = ev[t];
    int rk = 0;
    for (int j = 0; j < CH; ++j) {
      double o = ev[j];
      rk += (o > my || (o == my && j < t)) ? 1 : 0;
    }
    pm[rk] = t;
  }
  __syncthreads();
  if (t < CH) perm[t] = pm[t];
  for (int e = t; e < 192 * 192; e += 256) {
    int k = e / 192, i = e - k * 192;
    float v = 0.f;
    if (k < CH && i < CH) v = (float)(invs[k] * V[(size_t)k * CH + pm[i]]);
    Vw[e] = v;
  }
}

// ---------------- pcT = (Y V)^T : [CH][NPIX] ----------------
__global__ __launch_bounds__(256) void k_pc(const float* __restrict__ x,
                                            const float* __restrict__ Vw,
                                            float* __restrict__ pcT) {
  __shared__ float xs[16][65];
  __shared__ float vs[16][33];
  int n0 = blockIdx.x * 64, i0 = blockIdx.y * 32;
  int t = threadIdx.x;
  int tn = t & 15, ti = t >> 4;
  float acc[4][2] = {};
  for (int k0 = 0; k0 < 192; k0 += 16) {
    {
      int col = t & 15, row = t >> 4;
      #pragma unroll
      for (int rr = 0; rr < 4; ++rr) {
        int nn = row + rr * 16;
        int k = k0 + col;
        xs[col][nn] = (k < CH) ? x[(size_t)(n0 + nn) * CH + k] : 0.f;
      }
    }
    {
      int ii = t & 31, kk = t >> 5;
      vs[kk][ii] = Vw[(k0 + kk) * 192 + i0 + ii];
      vs[kk + 8][ii] = Vw[(k0 + kk + 8) * 192 + i0 + ii];
    }
    __syncthreads();
    #pragma unroll
    for (int kk = 0; kk < 16; ++kk) {
      float b0 = vs[kk][ti], b1 = vs[kk][ti + 16];
      #pragma unroll
      for (int rr = 0; rr < 4; ++rr) {
        float a = xs[kk][tn + rr * 16];
        acc[rr][0] += a * b0;
        acc[rr][1] += a * b1;
      }
    }
    __syncthreads();
  }
  #pragma unroll
  for (int rr = 0; rr < 4; ++rr)
    #pragma unroll
    for (int bb = 0; bb < 2; ++bb) {
      int i = i0 + ti + bb * 16, n = n0 + tn + rr * 16;
      if (i < CH) pcT[(size_t)i * NPIX + n] = acc[rr][bb];
    }
}

// ---------------- DWT row pass ----------------
__global__ __launch_bounds__(256) void k_row(const float* __restrict__ in,
                                             float* __restrict__ rb,
                                             int h, int w, int wd, int chS) {
  __shared__ float rowv[256];
  int bid = blockIdx.x;
  int c = bid / h, y = bid % h;
  const float* src = in + (size_t)c * chS + (size_t)y * w;
  int t = threadIdx.x;
  if (t < w) rowv[t] = src[t];
  __syncthreads();
  float* dst = rb + (size_t)(c * h + y) * (2 * wd);
  for (int o = t; o < 2 * wd; o += 256) {
    int b = (o >= wd) ? 1 : 0;
    int xp = b ? o - wd : o;
    float acc = 0.f;
    #pragma unroll
    for (int s = 0; s < 10; ++s) {
      int m = 2 * xp + 1 - s;
      if (m < 0) m = -1 - m;
      else if (m >= w) m = 2 * w - 1 - m;
      acc += (b ? g_dhi[s] : g_dlo[s]) * rowv[m];
    }
    dst[o] = acc;
  }
}

// ---------------- DWT column pass: LL out + high bands to coeff -----------
__global__ __launch_bounds__(256) void k_col(const float* __restrict__ rb,
                                             float* __restrict__ llout,
                                             float* __restrict__ coeff,
                                             int h, int wd, int hd, int chSout,
                                             int offHi, int offLL, int lastlvl) {
  int c = blockIdx.z, yp = blockIdx.y;
  int xq = blockIdx.x * 256 + threadIdx.x;
  if (xq >= 2 * wd) return;
  const float* base = rb + (size_t)c * h * 2 * wd + xq;
  float lo = 0.f, hi = 0.f;
  #pragma unroll
  for (int s = 0; s < 10; ++s) {
    int m = 2 * yp + 1 - s;
    if (m < 0) m = -1 - m;
    else if (m >= h) m = 2 * h - 1 - m;
    float v = base[(size_t)m * 2 * wd];
    lo += g_dlo[s] * v;
    hi += g_dhi[s] * v;
  }
  float* cc = coeff + (size_t)c * CSTRIDE;
  if (xq < wd) {
    llout[(size_t)c * chSout + (size_t)yp * wd + xq] = lo;
    if (lastlvl) cc[offLL + yp * wd + xq] = lo;
    cc[offHi + 0 * hd * wd + yp * wd + xq] = hi;
  } else {
    int xp = xq - wd;
    cc[offHi + 1 * hd * wd + yp * wd + xp] = lo;
    cc[offHi + 2 * hd * wd + yp * wd + xp] = hi;
  }
}

// ---------------- SURE statistics (per-thread accumulate, then reduce) ----
__global__ __launch_bounds__(256) void k_stats(const float* __restrict__ coeff,
                                               double* __restrict__ stats, TArgs ta) {
  int c = blockIdx.y;
  const float* cc = coeff + (size_t)c * CSTRIDE;
  double sm[15], cnt[15], nrm = 0;
  #pragma unroll
  for (int q = 0; q < 15; ++q) { sm[q] = 0; cnt[q] = 0; }
  for (int idx = blockIdx.x * 256 + threadIdx.x; idx < MCOEF; idx += 24 * 256) {
    double v = (double)cc[idx];
    double v2 = v * v;
    nrm += v2;
    #pragma unroll
    for (int q = 0; q < 15; ++q) {
      sm[q] += fmin(v2, ta.t2[q]);
      cnt[q] += (v2 >= ta.t2[q]) ? 1.0 : 0.0;
    }
  }
  __shared__ double wred[4][31];
  int lane = threadIdx.x & 63, wv = threadIdx.x >> 6;
  for (int q = 0; q < 31; ++q) {
    double val = (q < 15) ? sm[q] : ((q < 30) ? cnt[q - 15] : nrm);
    #pragma unroll
    for (int o = 32; o > 0; o >>= 1) val += __shfl_down(val, o);
    if (lane == 0) wred[wv][q] = val;
  }
  __syncthreads();
  if (threadIdx.x < 31) {
    double sum = wred[0][threadIdx.x] + wred[1][threadIdx.x] +
                 wred[2][threadIdx.x] + wred[3][threadIdx.x];
    atomicAdd(&stats[c * 31 + threadIdx.x], sum);
  }
}

// ---------------- SURE scan + rank + masked projection matrix -------------
__global__ __launch_bounds__(256) void k_sure(const double* __restrict__ stats,
                                              const double* __restrict__ sqrtom,
                                              const double* __restrict__ V,
                                              const int* __restrict__ perm,
                                              const int* __restrict__ min_iter_p,
                                              float* __restrict__ Wm,
                                              int* __restrict__ meta) {
  __shared__ double st[CH * 31];
  __shared__ double minsure[CH];
  __shared__ int rankS;
  int t = threadIdx.x;
  for (int e = t; e < CH * 31; e += 256) st[e] = stats[e];
  __syncthreads();
  if (t == 0) {
    double norm2 = 0;
    for (int c = 0; c < CH; ++c) norm2 += st[c * 31 + 30];
    double K = norm2 - (double)MCOEF * (double)CH;
    double cum[15];
    for (int q = 0; q < 15; ++q) cum[q] = 0;
    for (int r = 0; r < CH; ++r) {
      double mn = 1e300;
      for (int q = 0; q < 15; ++q) {
        double sure = st[r * 31 + q] + 2.0 * st[r * 31 + 15 + q] - (double)MCOEF;
        double s = cum[q] + sure + K;
        cum[q] += s;
        if (s < mn) mn = s;
      }
      minsure[r] = mn;
    }
    int mi = *min_iter_p;
    int rank = CH - 1;
    for (int r = 0; r < CH; ++r) {
      double prev = (r == 0) ? minsure[0] : minsure[r - 1];
      bool cond = (r > mi) && !(minsure[r] > 2.0 * prev);
      if (cond) { rank = r; break; }
    }
    rankS = rank;
    meta[1] = rank;
  }
  __syncthreads();
  int rank = rankS;
  for (int e = t; e < 192 * 192; e += 256) {
    int k = e / 192, c = e - k * 192;
    float v = 0.f;
    if (k < rank && c < CH) v = (float)(sqrtom[c] * V[(size_t)c * CH + perm[k]]);
    Wm[e] = v;
  }
}

// ---------------- out = pcT^T * Wm ----------------
__global__ __launch_bounds__(256) void k_out(const float* __restrict__ pcT,
                                             const float* __restrict__ Wm,
                                             float* __restrict__ out) {
  __shared__ float psx[16][65];
  __shared__ float wsx[16][33];
  int n0 = blockIdx.x * 64, c0 = blockIdx.y * 32;
  int t = threadIdx.x;
  int tc = t & 15, tn = t >> 4;
  float acc[4][2] = {};
  for (int k0 = 0; k0 < 192; k0 += 16) {
    {
      int nn = t & 63, kk0 = t >> 6;
      #pragma unroll
      for (int rr = 0; rr < 4; ++rr) {
        int kk = kk0 + rr * 4;
        int k = k0 + kk;
        psx[kk][nn] = (k < CH) ? pcT[(size_t)k * NPIX + n0 + nn] : 0.f;
      }
    }
    {
      int cc = t & 31, kk = t >> 5;
      wsx[kk][cc] = Wm[(k0 + kk) * 192 + c0 + cc];
      wsx[kk + 8][cc] = Wm[(k0 + kk + 8) * 192 + c0 + cc];
    }
    __syncthreads();
    #pragma unroll
    for (int kk = 0; kk < 16; ++kk) {
      float b0 = wsx[kk][tc], b1 = wsx[kk][tc + 16];
      #pragma unroll
      for (int rr = 0; rr < 4; ++rr) {
        float a = psx[kk][tn + rr * 16];
        acc[rr][0] += a * b0;
        acc[rr][1] += a * b1;
      }
    }
    __syncthreads();
  }
  #pragma unroll
  for (int rr = 0; rr < 4; ++rr)
    #pragma unroll
    for (int bb = 0; bb < 2; ++bb) {
      int n = n0 + tn + rr * 16, c = c0 + tc + bb * 16;
      if (c < CH) out[(size_t)n * CH + c] = acc[rr][bb];
    }
}

// ---------------- host ----------------
extern "C" void kernel_launch(void* const* d_in, const int* in_sizes, int n_in,
                              void* d_out, int out_size, void* d_ws, size_t ws_size,
                              hipStream_t stream) {
  const float* x = (const float*)d_in[0];
  const int* p_min_iter = (const int*)d_in[1];
  float* out = (float*)d_out;
  char* ws = (char*)d_ws;

  size_t cur = 0;
  auto A = [&](size_t b) { size_t o = cur; cur += (b + 511) & ~(size_t)511; return o; };
  double* ddp     = (double*)(ws + A((size_t)CH * CH * 8));
  double* ddpi64  = (double*)(ws + A((size_t)CH * CH * 8));
  double* Tm      = (double*)(ws + A((size_t)CH * CH * 8));
  double* V       = (double*)(ws + A((size_t)CH * CH * 8));
  double* G64     = (double*)(ws + A((size_t)CH * CH * 8));
  double* T64     = (double*)(ws + A((size_t)CH * CH * 8));
  double* Q       = (double*)(ws + A((size_t)CH * CH * 8));
  double* A2sk    = (double*)(ws + A((size_t)NSKEW * 8));
  double* dg64    = (double*)(ws + A((size_t)CH * 8));
  double* eig     = (double*)(ws + A((size_t)CH * 8));
  double* rsum    = (double*)(ws + A((size_t)CH * 8));
  double* sqrtom  = (double*)(ws + A((size_t)CH * 8));
  double* invs    = (double*)(ws + A((size_t)CH * 8));
  double* stats   = (double*)(ws + A((size_t)CH * 31 * 8));
  int* perm       = (int*)(ws + A((size_t)CH * 4));
  int* meta       = (int*)(ws + A(64));
  float* ddpi32   = (float*)(ws + A((size_t)CH * CH * 4));
  float* Gsk      = (float*)(ws + A((size_t)NSKEW * 4));
  float* dgf      = (float*)(ws + A((size_t)CH * 4));
  float* Vw       = (float*)(ws + A((size_t)192 * 192 * 4));
  float* Wm       = (float*)(ws + A((size_t)192 * 192 * 4));
  float2* rlogA   = (float2*)(ws + A((size_t)SW32 * CH * 95 * 8));
  double2* rlogB  = (double2*)(ws + A((size_t)CH * 95 * 16));
  float* pcT      = (float*)(ws + A((size_t)CH * NPIX * 4));
  float* rowbuf   = (float*)(ws + A((size_t)CH * 256 * 264 * 4));
  float* llA      = (float*)(ws + A((size_t)CH * 17424 * 4));
  float* llB      = (float*)(ws + A((size_t)CH * 4900 * 4));
  float* coeff    = (float*)(ws + A((size_t)CH * CSTRIDE * 4));
  (void)ws_size; (void)in_sizes; (void)n_in; (void)out_size;

  hipMemsetAsync(ddp, 0, (size_t)CH * CH * 8, stream);
  hipMemsetAsync(rsum, 0, (size_t)CH * 8, stream);
  hipMemsetAsync(stats, 0, (size_t)CH * 31 * 8, stream);

  const int GJ_SMEM = (CH * CH + CH) * 4;                       // 146688
  const int J32_SMEM = NSKEW * 4;                               // 74496
  const int J64_SMEM = NSKEW * 8;                               // 148992

  k_ddp<<<dim3(6, 6, 16), 256, 0, stream>>>(x, ddp);
  k_mirror<<<143, 256, 0, stream>>>(ddp);
  k_rsum<<<256, 256, 0, stream>>>(x, rsum);
  (void)hipFuncSetAttribute((const void*)k_gj,
        hipFuncAttributeMaxDynamicSharedMemorySize, GJ_SMEM);
  k_gj<<<1, 1024, GJ_SMEM, stream>>>(ddp, ddpi32);
  k_newton1<<<dim3(12, 12), dim3(16, 16), 0, stream>>>(ddp, ddpi32, Tm);
  k_newton2<<<dim3(12, 12), dim3(16, 16), 0, stream>>>(ddpi32, Tm, ddpi64);
  k_beta<<<CH, 256, 0, stream>>>(ddp, ddpi64, rsum, sqrtom, invs);
  k_packG<<<143, 256, 0, stream>>>(ddp, invs, Gsk, dgf, G64);
  (void)hipFuncSetAttribute((const void*)k_jac32,
        hipFuncAttributeMaxDynamicSharedMemorySize, J32_SMEM);
  k_jac32<<<1, 1024, J32_SMEM, stream>>>(Gsk, dgf, rlogA);
  k_replayA<<<CH, 128, 0, stream>>>(rlogA, Q);
  k_gq<<<dim3(12, 12), dim3(16, 16), 0, stream>>>(G64, Q, T64);
  k_qtq<<<dim3(12, 12), dim3(16, 16), 0, stream>>>(Q, T64, A2sk, dg64);
  (void)hipFuncSetAttribute((const void*)k_jac64,
        hipFuncAttributeMaxDynamicSharedMemorySize, J64_SMEM);
  k_jac64<<<1, 1024, J64_SMEM, stream>>>(A2sk, dg64, eig, rlogB);
  k_replayB<<<CH, 128, 0, stream>>>(rlogB, Q, V);
  k_sortprep<<<1, 256, 0, stream>>>(eig, V, invs, perm, Vw);
  k_pc<<<dim3(1024, 6), 256, 0, stream>>>(x, Vw, pcT);

  int hs[6] = {256, 132, 70, 39, 24, 16};
  int offHi[5];
  { int a0 = 0; for (int l = 0; l < 5; ++l) { offHi[l] = a0; a0 += 3 * hs[l + 1] * hs[l + 1]; } }
  const int offLL = 74031;
  float* lls[6] = {pcT, llA, llB, llA, llB, llA};
  for (int l = 0; l < 5; ++l) {
    int h = hs[l], w = hs[l], wd = hs[l + 1], hd = hs[l + 1];
    k_row<<<CH * h, 256, 0, stream>>>(lls[l], rowbuf, h, w, wd, h * w);
    k_col<<<dim3((2 * wd + 255) / 256, hd, CH), 256, 0, stream>>>(
        rowbuf, lls[l + 1], coeff, h, wd, hd, hd * wd, offHi[l], offLL,
        (l == 4) ? 1 : 0);
  }

  TArgs ta;
  {
    double tmax = sqrt(log((double)MCOEF));
    for (int j = 0; j < 15; ++j) { double tv = tmax * j / 14.0; ta.t2[j] = tv * tv; }
  }
  k_stats<<<dim3(24, CH), 256, 0, stream>>>(coeff, stats, ta);
  k_sure<<<1, 256, 0, stream>>>(stats, sqrtom, V, perm, p_min_iter, Wm, meta);
  k_out<<<dim3(1024, 6), 256, 0, stream>>>(pcT, Wm, out);
}